// Round 7
// baseline (381.189 us; speedup 1.0000x reference)
//
#include <hip/hip_runtime.h>
#include <math.h>

#define EPSF 1e-7f
#define Bsz 2
#define Cch 1024
#define Hh 60
#define Ssz 3600
#define HID 256
#define TDIM 300
#define MH 473

// pool tiling
#define TROWS 15
#define LROWS 21          // TROWS + 6 halo
#define LPITCH 68         // 4-col zero pad both sides of 60 cols
#define CPG 8             // channels per block (processed as 4 float2 pairs)

// workspace layout (float offsets)
#define OFF_PPOOL  0               // 128*2*3*3600 pool partials (non-atomic)
#define OFF_WMAP   2764800         // 6*3600  mask-premultiplied pool(1/sn)
#define OFF_V      2786400         // 6*1024
#define OFF_DOTP   2792544         // 16*2*3*3600 dot partials
#define OFF_NORM   3138144         // 6*3600 normalized sim planes
#define OFF_SCORE  3159744         // 2*3600
#define OFF_KBAR   3166944         // 2*256
#define OFF_CNT    3167456         // 8 ints: [0]=dot [1..2]=sim_b [4..5]=kbar_b

__device__ __forceinline__ void spin_until(int* p, int target) {
    while (__hip_atomic_load(p, __ATOMIC_ACQUIRE, __HIP_MEMORY_SCOPE_AGENT) < target)
        __builtin_amdgcn_s_sleep(10);
}
__device__ __forceinline__ void publish(int* p, int tid) {
    __threadfence();
    __syncthreads();
    if (tid == 0) __hip_atomic_fetch_add(p, 1, __ATOMIC_RELEASE, __HIP_MEMORY_SCOPE_AGENT);
}

// ---------------- pass A: per-(cg,b) pool^2 partials (no atomics) ----------
__global__ void __launch_bounds__(256) k_pool_sn2(const float* __restrict__ supp,
                                                  const float* __restrict__ masks,
                                                  float* __restrict__ ws) {
    __shared__ float  mk[LROWS * LPITCH];
    __shared__ float2 raw[LROWS * LPITCH];
    __shared__ float2 h5s[LROWS * LPITCH];
    __shared__ float2 h7s[LROWS * LPITCH];
    int tid = threadIdx.x;
    int tile = blockIdx.x;       // 0..3
    int cg = blockIdx.y;         // 0..127
    int b = blockIdx.z;          // 0..1
    int y0 = tile * TROWS;

    const float2 z2 = {0.f, 0.f};
    for (int i = tid; i < LROWS * LPITCH; i += 256) {
        mk[i] = 0.f; raw[i] = z2; h5s[i] = z2; h7s[i] = z2;
    }
    __syncthreads();

    int lr[5], lx[5]; bool lv[5], la[5];
    #pragma unroll
    for (int j = 0; j < 5; ++j) {
        int idx = tid + 256 * j;
        int r = idx / 60, x = idx - 60 * r;
        lr[j] = r; lx[j] = x;
        la[j] = idx < 1260;
        int iy = y0 - 3 + r;
        lv[j] = la[j] && (iy >= 0) && (iy < Hh);
    }
    #pragma unroll
    for (int j = 0; j < 5; ++j)
        if (lv[j]) {
            int iy = y0 - 3 + lr[j];
            mk[lr[j] * LPITCH + 4 + lx[j]] =
                masks[(size_t)b * MH * MH + (size_t)(iy * 8) * MH + lx[j] * 8];
        }

    int orow[4], ox[4]; bool ov[4];
    #pragma unroll
    for (int j = 0; j < 4; ++j) {
        int o = tid + 256 * j;
        int oy = o / 60, x = o - 60 * oy;
        orow[j] = oy + 3; ox[j] = x; ov[j] = o < 900;
    }
    float a0[4] = {0,0,0,0}, a1[4] = {0,0,0,0}, a2[4] = {0,0,0,0};

    const float* chbase = supp + ((size_t)b * Cch + (size_t)cg * CPG) * Ssz + (y0 - 3) * 60;
    float pf0[5], pf1[5];
    #pragma unroll
    for (int j = 0; j < 5; ++j) {
        pf0[j] = lv[j] ? chbase[tid + 256 * j] : 0.f;
        pf1[j] = lv[j] ? chbase[Ssz + tid + 256 * j] : 0.f;
    }

    for (int p = 0; p < CPG / 2; ++p) {
        __syncthreads();
        #pragma unroll
        for (int j = 0; j < 5; ++j)
            if (lv[j]) {
                float m = mk[lr[j] * LPITCH + 4 + lx[j]];
                raw[lr[j] * LPITCH + 4 + lx[j]] = make_float2(pf0[j] * m, pf1[j] * m);
            }
        __syncthreads();
        #pragma unroll
        for (int j = 0; j < 5; ++j)
            if (la[j]) {
                int base = lr[j] * LPITCH + 4 + lx[j];
                float2 m3 = raw[base - 3], m2 = raw[base - 2], m1 = raw[base - 1];
                float2 c0 = raw[base], p1 = raw[base + 1], p2 = raw[base + 2], p3 = raw[base + 3];
                float2 h5, h7;
                h5.x = m2.x + m1.x + c0.x + p1.x + p2.x;
                h5.y = m2.y + m1.y + c0.y + p1.y + p2.y;
                h7.x = h5.x + m3.x + p3.x;
                h7.y = h5.y + m3.y + p3.y;
                h5s[base] = h5; h7s[base] = h7;
            }
        __syncthreads();
        if (p + 1 < CPG / 2) {
            const float* nb = chbase + (size_t)(2 * p + 2) * Ssz;
            #pragma unroll
            for (int j = 0; j < 5; ++j) {
                pf0[j] = lv[j] ? nb[tid + 256 * j] : 0.f;
                pf1[j] = lv[j] ? nb[Ssz + tid + 256 * j] : 0.f;
            }
        }
        #pragma unroll
        for (int j = 0; j < 4; ++j)
            if (ov[j]) {
                int base = orow[j] * LPITCH + 4 + ox[j];
                float2 sa = h5s[base - 2*LPITCH], sb = h5s[base - LPITCH], sc0 = h5s[base];
                float2 sd = h5s[base + LPITCH], se = h5s[base + 2*LPITCH];
                float p55x = (sa.x + sb.x + sc0.x + sd.x + se.x) * (1.f / 25.f);
                float p55y = (sa.y + sb.y + sc0.y + sd.y + se.y) * (1.f / 25.f);
                float2 ra = raw[base - 3*LPITCH], rb = raw[base - 2*LPITCH], rc = raw[base - LPITCH];
                float2 rd = raw[base], re = raw[base + LPITCH], rf = raw[base + 2*LPITCH], rg = raw[base + 3*LPITCH];
                float p71x = (ra.x + rb.x + rc.x + rd.x + re.x + rf.x + rg.x) * (1.f / 7.f);
                float p71y = (ra.y + rb.y + rc.y + rd.y + re.y + rf.y + rg.y) * (1.f / 7.f);
                float2 h7v = h7s[base];
                float p17x = h7v.x * (1.f / 7.f), p17y = h7v.y * (1.f / 7.f);
                a0[j] += p55x * p55x + p55y * p55y;
                a1[j] += p71x * p71x + p71y * p71y;
                a2[j] += p17x * p17x + p17y * p17y;
            }
    }
    float* dst = ws + OFF_PPOOL + (size_t)(cg * 2 + b) * 3 * Ssz;
    #pragma unroll
    for (int j = 0; j < 4; ++j)
        if (ov[j]) {
            int q = (y0 + orow[j] - 3) * 60 + ox[j];
            dst[q] = a0[j]; dst[Ssz + q] = a1[j]; dst[2 * Ssz + q] = a2[j];
        }
}

// ---------------- wm[b][kt] = mask * pool_kt(1/sqrt(sum partials)) ----------
__global__ void k_wmap(const float* __restrict__ masks, float* __restrict__ ws) {
    __shared__ float inv[LROWS * LPITCH];
    int tile = blockIdx.x;       // 0..3
    int bk = blockIdx.y;         // 0..5 = b*3+kt
    int b = bk / 3, kt = bk % 3;
    int tid = threadIdx.x;
    int y0 = tile * TROWS;
    for (int i = tid; i < LROWS * LPITCH; i += 256) inv[i] = 0.f;
    __syncthreads();
    const float* pp = ws + OFF_PPOOL + (size_t)(b * 3 + kt) * Ssz;
    #pragma unroll
    for (int j = 0; j < 5; ++j) {
        int idx = tid + 256 * j;
        if (idx < 1260) {
            int r = idx / 60, x = idx - 60 * r;
            int iy = y0 - 3 + r;
            if (iy >= 0 && iy < Hh) {
                int q = iy * 60 + x;
                float s = 0.f;
                #pragma unroll 4
                for (int g = 0; g < 128; ++g) s += pp[(size_t)g * (6 * Ssz) + q];
                inv[r * LPITCH + 4 + x] = 1.0f / sqrtf(fmaxf(s, 1e-30f));
            }
        }
    }
    __syncthreads();
    int kh = (kt == 0) ? 5 : (kt == 1) ? 7 : 1;
    int kw = (kt == 0) ? 5 : (kt == 2) ? 7 : 1;
    int rh = kh / 2, rw = kw / 2;
    float norm = 1.f / (float)(kh * kw);
    #pragma unroll
    for (int j = 0; j < 4; ++j) {
        int o = tid + 256 * j;
        if (o < 900) {
            int oy = o / 60, x = o - 60 * oy;
            int base = (oy + 3) * LPITCH + 4 + x;
            float s = 0.f;
            for (int dy = -rh; dy <= rh; ++dy)
                for (int dx = -rw; dx <= rw; ++dx)
                    s += inv[base + dy * LPITCH + dx];
            int gy = y0 + oy;
            float m = masks[(size_t)b * MH * MH + (size_t)(gy * 8) * MH + x * 8];
            ws[OFF_WMAP + (size_t)bk * Ssz + gy * 60 + x] = s * norm * m;
        }
    }
}

// ---------------- v[b][kt][c] : 4 channels/block, wmap reused ---------------
__global__ void k_v(const float* __restrict__ supp, float* __restrict__ ws) {
    int cB = blockIdx.x, b = blockIdx.y;
    int tid = threadIdx.x, lane = tid & 63, w = tid >> 6;
    if (cB == 0 && b == 0 && tid < 3) ((int*)(ws + OFF_CNT))[tid] = 0;  // K4 counters
    int c0 = cB * 4;
    const float4* sp4 = (const float4*)(supp + ((size_t)b * Cch + c0) * Ssz);
    const float4* w04 = (const float4*)(ws + OFF_WMAP + (size_t)(b * 3 + 0) * Ssz);
    const float4* w14 = (const float4*)(ws + OFF_WMAP + (size_t)(b * 3 + 1) * Ssz);
    const float4* w24 = (const float4*)(ws + OFF_WMAP + (size_t)(b * 3 + 2) * Ssz);
    float a[4][3];
    #pragma unroll
    for (int cc = 0; cc < 4; ++cc) { a[cc][0] = 0; a[cc][1] = 0; a[cc][2] = 0; }
    #pragma unroll
    for (int j = 0; j < 4; ++j) {
        int idx = tid + 256 * j;
        if (idx < 900) {
            float4 g0 = w04[idx], g1 = w14[idx], g2 = w24[idx];
            #pragma unroll
            for (int cc = 0; cc < 4; ++cc) {
                float4 f = sp4[cc * 900 + idx];
                a[cc][0] += f.x * g0.x + f.y * g0.y + f.z * g0.z + f.w * g0.w;
                a[cc][1] += f.x * g1.x + f.y * g1.y + f.z * g1.z + f.w * g1.w;
                a[cc][2] += f.x * g2.x + f.y * g2.y + f.z * g2.z + f.w * g2.w;
            }
        }
    }
    #pragma unroll
    for (int m = 32; m >= 1; m >>= 1)
        #pragma unroll
        for (int cc = 0; cc < 4; ++cc) {
            a[cc][0] += __shfl_xor(a[cc][0], m, 64);
            a[cc][1] += __shfl_xor(a[cc][1], m, 64);
            a[cc][2] += __shfl_xor(a[cc][2], m, 64);
        }
    __shared__ float r[4][3][4];
    if (lane == 0)
        #pragma unroll
        for (int cc = 0; cc < 4; ++cc) {
            r[cc][0][w] = a[cc][0]; r[cc][1][w] = a[cc][1]; r[cc][2][w] = a[cc][2];
        }
    __syncthreads();
    if (tid < 12) {
        int cc = tid / 3, kk = tid - cc * 3;
        float s = r[cc][kk][0] + r[cc][kk][1] + r[cc][kk][2] + r[cc][kk][3];
        ws[OFF_V + (size_t)(b * 3 + kk) * Cch + c0 + cc] = s;
    }
}

// ---------------- fused dot -> sim -> final (counter-gated roles) -----------
__global__ void __launch_bounds__(1024) k_dotsim(const float* __restrict__ query,
                                                 const float* __restrict__ weight,
                                                 float* __restrict__ ws,
                                                 float* __restrict__ out) {
    __shared__ float sA[66 * LPITCH];   // dpad / vnsum
    __shared__ float sB[66 * LPITCH];   // hbuf
    __shared__ float rmin[16], rmax[16];
    int tid = threadIdx.x, bx = blockIdx.x;
    int lane = tid & 63, w = tid >> 6;
    int* cnt = (int*)(ws + OFF_CNT);

    if (bx < 128) {
        // ---- dot role: dotp[cc][b][kt][q-tile] ----
        int qt = bx & 3, cc = (bx >> 2) & 15, b = bx >> 6;
        int q = qt * 1024 + tid;
        if (q < Ssz) {
            const float* v0 = ws + OFF_V + (size_t)(b * 3 + 0) * Cch;
            const float* v1 = ws + OFF_V + (size_t)(b * 3 + 1) * Cch;
            const float* v2 = ws + OFF_V + (size_t)(b * 3 + 2) * Cch;
            float a0 = 0, a1 = 0, a2 = 0;
            int c0 = cc * 64;
            #pragma unroll 8
            for (int c = c0; c < c0 + 64; ++c) {
                float qv = query[((size_t)b * Cch + c) * Ssz + q];
                a0 += qv * v0[c]; a1 += qv * v1[c]; a2 += qv * v2[c];
            }
            float* dst = ws + OFF_DOTP + (size_t)((cc * 2 + b) * 3) * Ssz + q;
            dst[0] = a0; dst[Ssz] = a1; dst[2 * Ssz] = a2;
        }
        publish(&cnt[0], tid);
    } else if (bx < 134) {
        // ---- sim role: one block per (b,kt) ----
        int bk = bx - 128; int b = bk / 3; int kt = bk % 3;
        spin_until(&cnt[0], 128);
        const float* dp0 = ws + OFF_DOTP + (size_t)(b * 3 + kt) * Ssz;
        for (int i = tid; i < 66 * LPITCH; i += 1024) {
            int r = i / LPITCH, col = i - r * LPITCH;
            int y = r - 3, x = col - 4;
            float s = 0.f;
            if (y >= 0 && y < Hh && x >= 0 && x < Hh) {
                int q = y * Hh + x;
                #pragma unroll
                for (int g = 0; g < 16; ++g) s += dp0[(size_t)g * 6 * Ssz + q];
            }
            sA[i] = s;
        }
        __syncthreads();
        if (kt != 1) {
            for (int idx = tid; idx < 66 * 60; idx += 1024) {
                int r = idx / 60, x = idx - 60 * r;
                int base = r * LPITCH + 4 + x;
                if (kt == 0)
                    sB[base] = sA[base - 2] + sA[base - 1] + sA[base] + sA[base + 1] + sA[base + 2];
                else
                    sB[base] = sA[base - 3] + sA[base - 2] + sA[base - 1] + sA[base]
                             + sA[base + 1] + sA[base + 2] + sA[base + 3];
            }
        }
        __syncthreads();
        float norm = ((kt == 0) ? (1.f / 25.f) : (1.f / 7.f)) * (1.f / (float)Ssz);
        float vals[4];
        float vmin = INFINITY, vmax = -INFINITY;
        #pragma unroll
        for (int j = 0; j < 4; ++j) {
            int q = tid + j * 1024;
            if (q < Ssz) {
                int y = q / Hh, x = q - y * Hh;
                int base = (y + 3) * LPITCH + 4 + x;
                float s;
                if (kt == 0)
                    s = sB[base - 2*LPITCH] + sB[base - LPITCH] + sB[base]
                      + sB[base + LPITCH] + sB[base + 2*LPITCH];
                else if (kt == 1)
                    s = sA[base - 3*LPITCH] + sA[base - 2*LPITCH] + sA[base - LPITCH]
                      + sA[base] + sA[base + LPITCH] + sA[base + 2*LPITCH] + sA[base + 3*LPITCH];
                else
                    s = sB[base];
                float val = s * norm;
                vals[j] = val;
                vmin = fminf(vmin, val); vmax = fmaxf(vmax, val);
            }
        }
        #pragma unroll
        for (int m = 32; m >= 1; m >>= 1) {
            vmin = fminf(vmin, __shfl_xor(vmin, m, 64));
            vmax = fmaxf(vmax, __shfl_xor(vmax, m, 64));
        }
        if (lane == 0) { rmin[w] = vmin; rmax[w] = vmax; }
        __syncthreads();
        float mn = rmin[0], mx = rmax[0];
        #pragma unroll
        for (int ww = 1; ww < 16; ++ww) {
            mn = fminf(mn, rmin[ww]); mx = fmaxf(mx, rmax[ww]);
        }
        float inv = 1.f / (mx - mn + EPSF);
        float* np = ws + OFF_NORM + (size_t)(b * 3 + kt) * Ssz;
        #pragma unroll
        for (int j = 0; j < 4; ++j) {
            int q = tid + j * 1024;
            if (q < Ssz) np[q] = (vals[j] - mn) * inv;
        }
        publish(&cnt[1 + b], tid);
    } else {
        // ---- final role: one block per b ----
        int b = bx - 134;
        spin_until(&cnt[1 + b], 3);
        float wq3 = weight[b] * (1.f / 3.f);
        const float* n0 = ws + OFF_NORM + (size_t)(b * 3 + 0) * Ssz;
        const float* n1 = ws + OFF_NORM + (size_t)(b * 3 + 1) * Ssz;
        const float* n2 = ws + OFF_NORM + (size_t)(b * 3 + 2) * Ssz;
        #pragma unroll
        for (int j = 0; j < 4; ++j) {
            int q = tid + j * 1024;
            if (q < Ssz) {
                float s = n0[q] + n1[q] + n2[q];
                sA[q] = s;
                out[b * Ssz + q] = wq3 * s;
            }
        }
        __syncthreads();
        #pragma unroll
        for (int j = 0; j < 2; ++j) {
            int o = tid + j * 1024;
            if (o >= 1189) continue;
            int O, p, outi;
            if (o < 900)       { O = 30; p = o;        outi = 7200 + b * 900 + p; }
            else if (o < 1125) { O = 15; p = o - 900;  outi = 9000 + b * 225 + p; }
            else               { O = 8;  p = o - 1125; outi = 9450 + b * 64 + p; }
            int y = p / O, x = p - y * O;
            float sc = 59.f / (float)(O - 1);
            float py = y * sc, px = x * sc;
            int y0 = (int)floorf(py), x0 = (int)floorf(px);
            int y1 = min(y0 + 1, 59), x1 = min(x0 + 1, 59);
            float wy = py - y0, wx = px - x0;
            float v = sA[y0 * 60 + x0] * (1.f - wy) * (1.f - wx)
                    + sA[y1 * 60 + x0] * wy * (1.f - wx)
                    + sA[y0 * 60 + x1] * (1.f - wy) * wx
                    + sA[y1 * 60 + x1] * wy * wx;
            out[outi] = wq3 * v;
        }
    }
}

// ---------------- APA: u (redundant per block) + score strip ----------------
__global__ void __launch_bounds__(1024, 1)
k_apascore(const float* __restrict__ text, const float* __restrict__ proto,
           const float* __restrict__ w_q, const float* __restrict__ w_bl,
           const float* __restrict__ w_k, const float* __restrict__ kin,
           float* __restrict__ ws) {
    int st = blockIdx.x, b = blockIdx.y;
    int tid = threadIdx.x;
    int lane = tid & 63, w = tid >> 6;
    if (st == 0 && b == 0 && tid < 2) ((int*)(ws + OFF_CNT))[4 + tid] = 0;  // kbar counters
    __shared__ float4 p4[16][64];
    __shared__ float qxs[256], qws[256], us[256];
    const float4* wq4 = (const float4*)w_q;
    const float4* wbl4 = (const float4*)w_bl;
    const float4* wk4 = (const float4*)w_k;

    float4 acc = {0.f, 0.f, 0.f, 0.f};
    #pragma unroll
    for (int j = 0; j < 35; ++j) {
        int e = w + 16 * j;
        if (e < TDIM + HID) {
            float x = (e < TDIM) ? text[b * TDIM + e] : proto[b * HID + e - TDIM];
            float4 f = wq4[(size_t)e * 64 + lane];
            acc.x += x * f.x; acc.y += x * f.y; acc.z += x * f.z; acc.w += x * f.w;
        }
    }
    p4[w][lane] = acc;
    __syncthreads();
    if (tid < 256) {
        const float* pf = (const float*)p4;
        float s = 0.f;
        #pragma unroll
        for (int ww = 0; ww < 16; ++ww) s += pf[ww * 256 + tid];
        qxs[tid] = s;
    }
    __syncthreads();

    acc.x = acc.y = acc.z = acc.w = 0.f;
    #pragma unroll
    for (int j = 0; j < 16; ++j) {
        int e = w + 16 * j;
        float x = qxs[e];
        float4 f = wbl4[(size_t)e * 64 + lane];
        acc.x += x * f.x; acc.y += x * f.y; acc.z += x * f.z; acc.w += x * f.w;
    }
    p4[w][lane] = acc;
    __syncthreads();
    if (tid < 256) {
        const float* pf = (const float*)p4;
        float s = 0.f;
        #pragma unroll
        for (int ww = 0; ww < 16; ++ww) s += pf[ww * 256 + tid];
        qws[tid] = s;
    }
    __syncthreads();

    acc.x = acc.y = acc.z = acc.w = 0.f;
    #pragma unroll
    for (int j = 0; j < 16; ++j) {
        int e = w + 16 * j;
        float x = qws[e];
        float4 f = wk4[(size_t)e * 64 + lane];
        acc.x += x * f.x; acc.y += x * f.y; acc.z += x * f.z; acc.w += x * f.w;
    }
    p4[w][lane] = acc;
    __syncthreads();
    if (tid < 256) {
        const float* pf = (const float*)p4;
        float s = 0.f;
        #pragma unroll
        for (int ww = 0; ww < 16; ++ww) s += pf[ww * 256 + tid];
        us[tid] = s;
    }
    __syncthreads();

    // score strip: s = st*240 + (tid>>2), 4-way split over i
    int sl = tid >> 2, part = tid & 3;
    if (sl < 240) {
        int s = st * 240 + sl;
        const float* kb = kin + ((size_t)b * HID + part * 64) * Ssz + s;
        const float* up = us + part * 64;
        float a = 0.f;
        #pragma unroll 8
        for (int i = 0; i < 64; ++i) a += up[i] * kb[(size_t)i * Ssz];
        a += __shfl_xor(a, 1, 64);
        a += __shfl_xor(a, 2, 64);
        if (part == 0) ws[OFF_SCORE + (size_t)b * Ssz + s] = a;
    }
}

// ---------------- kbar (fused softmax) + gated apa_out epilogue -------------
__global__ void __launch_bounds__(256)
k_kbarout(const float* __restrict__ kin, const float* __restrict__ w_k,
          const float* __restrict__ w_proj, const float* __restrict__ b_proj,
          const float* __restrict__ proto, float* __restrict__ ws,
          float* __restrict__ out) {
    int bx = blockIdx.x, tid = threadIdx.x;
    int lane = tid & 63, w = tid >> 6;
    int* cnt = (int*)(ws + OFF_CNT);
    if (bx < 512) {
        int i = bx >> 1, b = bx & 1;
        __shared__ float r1[4], r2[4];
        const float4* s4 = (const float4*)(ws + OFF_SCORE + (size_t)b * Ssz);
        float4 sv[4]; bool act[4];
        float mx = -INFINITY;
        #pragma unroll
        for (int j = 0; j < 4; ++j) {
            int idx = tid + 256 * j;
            act[j] = idx < 900;
            if (act[j]) {
                float4 v = s4[idx];
                sv[j] = v;
                mx = fmaxf(mx, fmaxf(fmaxf(v.x, v.y), fmaxf(v.z, v.w)));
            }
        }
        #pragma unroll
        for (int m = 32; m >= 1; m >>= 1) mx = fmaxf(mx, __shfl_xor(mx, m, 64));
        if (lane == 0) r1[w] = mx;
        __syncthreads();
        mx = fmaxf(fmaxf(r1[0], r1[1]), fmaxf(r1[2], r1[3]));
        __syncthreads();
        const float4* kr = (const float4*)(kin + ((size_t)b * HID + i) * Ssz);
        float se = 0.f, wsum = 0.f;
        #pragma unroll
        for (int j = 0; j < 4; ++j) {
            if (act[j]) {
                int idx = tid + 256 * j;
                float4 v = sv[j];
                float ex = expf(v.x - mx), ey = expf(v.y - mx);
                float ez = expf(v.z - mx), ew = expf(v.w - mx);
                se += ex + ey + ez + ew;
                float4 k4 = kr[idx];
                wsum += ex * k4.x + ey * k4.y + ez * k4.z + ew * k4.w;
            }
        }
        #pragma unroll
        for (int m = 32; m >= 1; m >>= 1) {
            se += __shfl_xor(se, m, 64);
            wsum += __shfl_xor(wsum, m, 64);
        }
        if (lane == 0) { r1[w] = se; r2[w] = wsum; }
        __syncthreads();
        if (tid == 0) {
            float seT = r1[0] + r1[1] + r1[2] + r1[3];
            float wsT = r2[0] + r2[1] + r2[2] + r2[3];
            ws[OFF_KBAR + b * HID + i] = wsT / seT;
        }
        publish(&cnt[4 + b], tid);
    } else {
        int b = bx - 512;
        spin_until(&cnt[4 + b], 256);
        __shared__ float4 kbs[64];
        __shared__ float o1s[256];
        if (tid < 64) kbs[tid] = ((const float4*)(ws + OFF_KBAR + b * HID))[tid];
        __syncthreads();
        const float4* wk4 = (const float4*)w_k;
        float4 kb4 = kbs[lane];
        // 4 waves x 64 rows each
        #pragma unroll 8
        for (int r = 0; r < 64; ++r) {
            int h = w * 64 + r;
            float4 f = wk4[(size_t)h * 64 + lane];
            float p = f.x * kb4.x + f.y * kb4.y + f.z * kb4.z + f.w * kb4.w;
            #pragma unroll
            for (int m = 32; m >= 1; m >>= 1) p += __shfl_xor(p, m, 64);
            if (lane == 0) o1s[h] = p;
        }
        __syncthreads();
        float a2 = b_proj[tid] + proto[b * HID + tid];
        #pragma unroll 8
        for (int d = 0; d < 256; ++d) a2 += o1s[d] * w_proj[(size_t)d * HID + tid];
        out[9578 + b * HID + tid] = a2;
    }
}

extern "C" void kernel_launch(void* const* d_in, const int* in_sizes, int n_in,
                              void* d_out, int out_size, void* d_ws, size_t ws_size,
                              hipStream_t stream) {
    const float* weight = (const float*)d_in[0];
    const float* query  = (const float*)d_in[1];
    const float* supp   = (const float*)d_in[2];
    const float* masks  = (const float*)d_in[3];
    const float* kin    = (const float*)d_in[4];
    const float* text   = (const float*)d_in[5];
    const float* proto  = (const float*)d_in[6];
    const float* w_q    = (const float*)d_in[7];
    const float* w_k    = (const float*)d_in[8];
    const float* w_bl   = (const float*)d_in[9];
    const float* w_proj = (const float*)d_in[10];
    const float* b_proj = (const float*)d_in[11];
    float* out = (float*)d_out;
    float* ws  = (float*)d_ws;

    k_pool_sn2<<<dim3(4, 128, 2), 256, 0, stream>>>(supp, masks, ws);
    k_wmap<<<dim3(4, 6), 256, 0, stream>>>(masks, ws);
    k_v<<<dim3(256, 2), 256, 0, stream>>>(supp, ws);
    k_dotsim<<<136, 1024, 0, stream>>>(query, weight, ws, out);
    k_apascore<<<dim3(15, 2), 1024, 0, stream>>>(text, proto, w_q, w_bl, w_k, kin, ws);
    k_kbarout<<<514, 256, 0, stream>>>(kin, w_k, w_proj, b_proj, proto, ws, out);
}

// Round 8
// 258.093 us; speedup vs baseline: 1.4769x; 1.4769x over previous
//
#include <hip/hip_runtime.h>
#include <math.h>

#define EPSF 1e-7f
#define Bsz 2
#define Cch 1024
#define Hh 60
#define Ssz 3600
#define HID 256
#define TDIM 300
#define MH 473

// pool tiling
#define TROWS 15
#define LROWS 21          // TROWS + 6 halo
#define LPITCH 68         // 4-col zero pad both sides of 60 cols
#define CPG 8             // channels per block (processed as 4 float2 pairs)

// workspace layout (float offsets) -- no counters, no zeroing needed
#define OFF_PPOOL  0               // 128*2*3*3600 pool partials (non-atomic)
#define OFF_WMAP   2764800         // 6*3600  mask-premultiplied pool(1/sn)
#define OFF_V      2786400         // 6*1024
#define OFF_DOTP   2792544         // 16*2*3*3600 dot partials
#define OFF_NORM   3138144         // 6*3600 normalized sim planes
#define OFF_SCORE  3159744         // 2*3600
#define OFF_KBAR   3166944         // 2*256

// ---------------- pass A: per-(cg,b) pool^2 partials (no atomics) ----------
__global__ void __launch_bounds__(256) k_pool_sn2(const float* __restrict__ supp,
                                                  const float* __restrict__ masks,
                                                  float* __restrict__ ws) {
    __shared__ float  mk[LROWS * LPITCH];
    __shared__ float2 raw[LROWS * LPITCH];
    __shared__ float2 h5s[LROWS * LPITCH];
    __shared__ float2 h7s[LROWS * LPITCH];
    int tid = threadIdx.x;
    int tile = blockIdx.x;       // 0..3
    int cg = blockIdx.y;         // 0..127
    int b = blockIdx.z;          // 0..1
    int y0 = tile * TROWS;

    const float2 z2 = {0.f, 0.f};
    for (int i = tid; i < LROWS * LPITCH; i += 256) {
        mk[i] = 0.f; raw[i] = z2; h5s[i] = z2; h7s[i] = z2;
    }
    __syncthreads();

    int lr[5], lx[5]; bool lv[5], la[5];
    #pragma unroll
    for (int j = 0; j < 5; ++j) {
        int idx = tid + 256 * j;
        int r = idx / 60, x = idx - 60 * r;
        lr[j] = r; lx[j] = x;
        la[j] = idx < 1260;
        int iy = y0 - 3 + r;
        lv[j] = la[j] && (iy >= 0) && (iy < Hh);
    }
    #pragma unroll
    for (int j = 0; j < 5; ++j)
        if (lv[j]) {
            int iy = y0 - 3 + lr[j];
            mk[lr[j] * LPITCH + 4 + lx[j]] =
                masks[(size_t)b * MH * MH + (size_t)(iy * 8) * MH + lx[j] * 8];
        }

    int orow[4], ox[4]; bool ov[4];
    #pragma unroll
    for (int j = 0; j < 4; ++j) {
        int o = tid + 256 * j;
        int oy = o / 60, x = o - 60 * oy;
        orow[j] = oy + 3; ox[j] = x; ov[j] = o < 900;
    }
    float a0[4] = {0,0,0,0}, a1[4] = {0,0,0,0}, a2[4] = {0,0,0,0};

    const float* chbase = supp + ((size_t)b * Cch + (size_t)cg * CPG) * Ssz + (y0 - 3) * 60;
    float pf0[5], pf1[5];
    #pragma unroll
    for (int j = 0; j < 5; ++j) {
        pf0[j] = lv[j] ? chbase[tid + 256 * j] : 0.f;
        pf1[j] = lv[j] ? chbase[Ssz + tid + 256 * j] : 0.f;
    }

    for (int p = 0; p < CPG / 2; ++p) {
        __syncthreads();
        #pragma unroll
        for (int j = 0; j < 5; ++j)
            if (lv[j]) {
                float m = mk[lr[j] * LPITCH + 4 + lx[j]];
                raw[lr[j] * LPITCH + 4 + lx[j]] = make_float2(pf0[j] * m, pf1[j] * m);
            }
        __syncthreads();
        #pragma unroll
        for (int j = 0; j < 5; ++j)
            if (la[j]) {
                int base = lr[j] * LPITCH + 4 + lx[j];
                float2 m3 = raw[base - 3], m2 = raw[base - 2], m1 = raw[base - 1];
                float2 c0 = raw[base], p1 = raw[base + 1], p2 = raw[base + 2], p3 = raw[base + 3];
                float2 h5, h7;
                h5.x = m2.x + m1.x + c0.x + p1.x + p2.x;
                h5.y = m2.y + m1.y + c0.y + p1.y + p2.y;
                h7.x = h5.x + m3.x + p3.x;
                h7.y = h5.y + m3.y + p3.y;
                h5s[base] = h5; h7s[base] = h7;
            }
        __syncthreads();
        if (p + 1 < CPG / 2) {
            const float* nb = chbase + (size_t)(2 * p + 2) * Ssz;
            #pragma unroll
            for (int j = 0; j < 5; ++j) {
                pf0[j] = lv[j] ? nb[tid + 256 * j] : 0.f;
                pf1[j] = lv[j] ? nb[Ssz + tid + 256 * j] : 0.f;
            }
        }
        #pragma unroll
        for (int j = 0; j < 4; ++j)
            if (ov[j]) {
                int base = orow[j] * LPITCH + 4 + ox[j];
                float2 sa = h5s[base - 2*LPITCH], sb = h5s[base - LPITCH], sc0 = h5s[base];
                float2 sd = h5s[base + LPITCH], se = h5s[base + 2*LPITCH];
                float p55x = (sa.x + sb.x + sc0.x + sd.x + se.x) * (1.f / 25.f);
                float p55y = (sa.y + sb.y + sc0.y + sd.y + se.y) * (1.f / 25.f);
                float2 ra = raw[base - 3*LPITCH], rb = raw[base - 2*LPITCH], rc = raw[base - LPITCH];
                float2 rd = raw[base], re = raw[base + LPITCH], rf = raw[base + 2*LPITCH], rg = raw[base + 3*LPITCH];
                float p71x = (ra.x + rb.x + rc.x + rd.x + re.x + rf.x + rg.x) * (1.f / 7.f);
                float p71y = (ra.y + rb.y + rc.y + rd.y + re.y + rf.y + rg.y) * (1.f / 7.f);
                float2 h7v = h7s[base];
                float p17x = h7v.x * (1.f / 7.f), p17y = h7v.y * (1.f / 7.f);
                a0[j] += p55x * p55x + p55y * p55y;
                a1[j] += p71x * p71x + p71y * p71y;
                a2[j] += p17x * p17x + p17y * p17y;
            }
    }
    float* dst = ws + OFF_PPOOL + (size_t)(cg * 2 + b) * 3 * Ssz;
    #pragma unroll
    for (int j = 0; j < 4; ++j)
        if (ov[j]) {
            int q = (y0 + orow[j] - 3) * 60 + ox[j];
            dst[q] = a0[j]; dst[Ssz + q] = a1[j]; dst[2 * Ssz + q] = a2[j];
        }
}

// ---------------- wm[b][kt] = mask * pool_kt(1/sqrt(sum partials)) ----------
__global__ void k_wmap(const float* __restrict__ masks, float* __restrict__ ws) {
    __shared__ float inv[LROWS * LPITCH];
    int tile = blockIdx.x;       // 0..3
    int bk = blockIdx.y;         // 0..5 = b*3+kt
    int b = bk / 3, kt = bk % 3;
    int tid = threadIdx.x;
    int y0 = tile * TROWS;
    for (int i = tid; i < LROWS * LPITCH; i += 256) inv[i] = 0.f;
    __syncthreads();
    const float* pp = ws + OFF_PPOOL + (size_t)(b * 3 + kt) * Ssz;
    #pragma unroll
    for (int j = 0; j < 5; ++j) {
        int idx = tid + 256 * j;
        if (idx < 1260) {
            int r = idx / 60, x = idx - 60 * r;
            int iy = y0 - 3 + r;
            if (iy >= 0 && iy < Hh) {
                int q = iy * 60 + x;
                float s = 0.f;
                #pragma unroll 4
                for (int g = 0; g < 128; ++g) s += pp[(size_t)g * (6 * Ssz) + q];
                inv[r * LPITCH + 4 + x] = 1.0f / sqrtf(fmaxf(s, 1e-30f));
            }
        }
    }
    __syncthreads();
    int kh = (kt == 0) ? 5 : (kt == 1) ? 7 : 1;
    int kw = (kt == 0) ? 5 : (kt == 2) ? 7 : 1;
    int rh = kh / 2, rw = kw / 2;
    float norm = 1.f / (float)(kh * kw);
    #pragma unroll
    for (int j = 0; j < 4; ++j) {
        int o = tid + 256 * j;
        if (o < 900) {
            int oy = o / 60, x = o - 60 * oy;
            int base = (oy + 3) * LPITCH + 4 + x;
            float s = 0.f;
            for (int dy = -rh; dy <= rh; ++dy)
                for (int dx = -rw; dx <= rw; ++dx)
                    s += inv[base + dy * LPITCH + dx];
            int gy = y0 + oy;
            float m = masks[(size_t)b * MH * MH + (size_t)(gy * 8) * MH + x * 8];
            ws[OFF_WMAP + (size_t)bk * Ssz + gy * 60 + x] = s * norm * m;
        }
    }
}

// ---------------- v[b][kt][c] : 4 channels/block, wmap reused ---------------
__global__ void k_v(const float* __restrict__ supp, float* __restrict__ ws) {
    int cB = blockIdx.x, b = blockIdx.y;
    int tid = threadIdx.x, lane = tid & 63, w = tid >> 6;
    int c0 = cB * 4;
    const float4* sp4 = (const float4*)(supp + ((size_t)b * Cch + c0) * Ssz);
    const float4* w04 = (const float4*)(ws + OFF_WMAP + (size_t)(b * 3 + 0) * Ssz);
    const float4* w14 = (const float4*)(ws + OFF_WMAP + (size_t)(b * 3 + 1) * Ssz);
    const float4* w24 = (const float4*)(ws + OFF_WMAP + (size_t)(b * 3 + 2) * Ssz);
    float a[4][3];
    #pragma unroll
    for (int cc = 0; cc < 4; ++cc) { a[cc][0] = 0; a[cc][1] = 0; a[cc][2] = 0; }
    #pragma unroll
    for (int j = 0; j < 4; ++j) {
        int idx = tid + 256 * j;
        if (idx < 900) {
            float4 g0 = w04[idx], g1 = w14[idx], g2 = w24[idx];
            #pragma unroll
            for (int cc = 0; cc < 4; ++cc) {
                float4 f = sp4[cc * 900 + idx];
                a[cc][0] += f.x * g0.x + f.y * g0.y + f.z * g0.z + f.w * g0.w;
                a[cc][1] += f.x * g1.x + f.y * g1.y + f.z * g1.z + f.w * g1.w;
                a[cc][2] += f.x * g2.x + f.y * g2.y + f.z * g2.z + f.w * g2.w;
            }
        }
    }
    #pragma unroll
    for (int m = 32; m >= 1; m >>= 1)
        #pragma unroll
        for (int cc = 0; cc < 4; ++cc) {
            a[cc][0] += __shfl_xor(a[cc][0], m, 64);
            a[cc][1] += __shfl_xor(a[cc][1], m, 64);
            a[cc][2] += __shfl_xor(a[cc][2], m, 64);
        }
    __shared__ float r[4][3][4];
    if (lane == 0)
        #pragma unroll
        for (int cc = 0; cc < 4; ++cc) {
            r[cc][0][w] = a[cc][0]; r[cc][1][w] = a[cc][1]; r[cc][2][w] = a[cc][2];
        }
    __syncthreads();
    if (tid < 12) {
        int cc = tid / 3, kk = tid - cc * 3;
        float s = r[cc][kk][0] + r[cc][kk][1] + r[cc][kk][2] + r[cc][kk][3];
        ws[OFF_V + (size_t)(b * 3 + kk) * Cch + c0 + cc] = s;
    }
}

// ---------------- dotp[cc][b][kt][q] = sum_{c in cc} query[c,q]*v[kt][c] ----
__global__ void k_dot(const float* __restrict__ query, float* __restrict__ ws) {
    int qt = blockIdx.x, cc = blockIdx.y, b = blockIdx.z;
    int q = qt * 256 + threadIdx.x;
    if (q >= Ssz) return;
    const float* v0 = ws + OFF_V + (size_t)(b * 3 + 0) * Cch;
    const float* v1 = ws + OFF_V + (size_t)(b * 3 + 1) * Cch;
    const float* v2 = ws + OFF_V + (size_t)(b * 3 + 2) * Cch;
    float a0 = 0, a1 = 0, a2 = 0;
    int c0 = cc * 64;
    #pragma unroll 8
    for (int c = c0; c < c0 + 64; ++c) {
        float qv = query[((size_t)b * Cch + c) * Ssz + q];
        a0 += qv * v0[c]; a1 += qv * v1[c]; a2 += qv * v2[c];
    }
    float* dst = ws + OFF_DOTP + (size_t)((cc * 2 + b) * 3) * Ssz + q;
    dst[0] = a0; dst[Ssz] = a1; dst[2 * Ssz] = a2;
}

// ---------------- sim: sum partials, pool, minmax-norm -> NORM planes -------
__global__ void __launch_bounds__(1024) k_sim(float* __restrict__ ws) {
    __shared__ float sA[66 * LPITCH];
    __shared__ float sB[66 * LPITCH];
    __shared__ float rmin[16], rmax[16];
    int bk = blockIdx.x; int b = bk / 3; int kt = bk % 3;
    int tid = threadIdx.x;
    int lane = tid & 63, w = tid >> 6;

    const float* dp0 = ws + OFF_DOTP + (size_t)(b * 3 + kt) * Ssz;
    for (int i = tid; i < 66 * LPITCH; i += 1024) {
        int r = i / LPITCH, col = i - r * LPITCH;
        int y = r - 3, x = col - 4;
        float s = 0.f;
        if (y >= 0 && y < Hh && x >= 0 && x < Hh) {
            int q = y * Hh + x;
            #pragma unroll
            for (int g = 0; g < 16; ++g) s += dp0[(size_t)g * 6 * Ssz + q];
        }
        sA[i] = s;
    }
    __syncthreads();
    if (kt != 1) {
        for (int idx = tid; idx < 66 * 60; idx += 1024) {
            int r = idx / 60, x = idx - 60 * r;
            int base = r * LPITCH + 4 + x;
            if (kt == 0)
                sB[base] = sA[base - 2] + sA[base - 1] + sA[base] + sA[base + 1] + sA[base + 2];
            else
                sB[base] = sA[base - 3] + sA[base - 2] + sA[base - 1] + sA[base]
                         + sA[base + 1] + sA[base + 2] + sA[base + 3];
        }
    }
    __syncthreads();
    float norm = ((kt == 0) ? (1.f / 25.f) : (1.f / 7.f)) * (1.f / (float)Ssz);
    float vals[4];
    float vmin = INFINITY, vmax = -INFINITY;
    #pragma unroll
    for (int j = 0; j < 4; ++j) {
        int q = tid + j * 1024;
        if (q < Ssz) {
            int y = q / Hh, x = q - y * Hh;
            int base = (y + 3) * LPITCH + 4 + x;
            float s;
            if (kt == 0)
                s = sB[base - 2*LPITCH] + sB[base - LPITCH] + sB[base]
                  + sB[base + LPITCH] + sB[base + 2*LPITCH];
            else if (kt == 1)
                s = sA[base - 3*LPITCH] + sA[base - 2*LPITCH] + sA[base - LPITCH]
                  + sA[base] + sA[base + LPITCH] + sA[base + 2*LPITCH] + sA[base + 3*LPITCH];
            else
                s = sB[base];
            float val = s * norm;
            vals[j] = val;
            vmin = fminf(vmin, val); vmax = fmaxf(vmax, val);
        }
    }
    #pragma unroll
    for (int m = 32; m >= 1; m >>= 1) {
        vmin = fminf(vmin, __shfl_xor(vmin, m, 64));
        vmax = fmaxf(vmax, __shfl_xor(vmax, m, 64));
    }
    if (lane == 0) { rmin[w] = vmin; rmax[w] = vmax; }
    __syncthreads();
    float mn = rmin[0], mx = rmax[0];
    #pragma unroll
    for (int ww = 1; ww < 16; ++ww) {
        mn = fminf(mn, rmin[ww]); mx = fmaxf(mx, rmax[ww]);
    }
    float inv = 1.f / (mx - mn + EPSF);
    float* np = ws + OFF_NORM + (size_t)(b * 3 + kt) * Ssz;
    #pragma unroll
    for (int j = 0; j < 4; ++j) {
        int q = tid + j * 1024;
        if (q < Ssz) np[q] = (vals[j] - mn) * inv;
    }
}

// ---------------- APA u + score strips, plus corr-final role (st==8) --------
// runs after k_sim (stream order): final role reads NORM planes safely.
__global__ void __launch_bounds__(1024, 1)
k_apascore(const float* __restrict__ text, const float* __restrict__ proto,
           const float* __restrict__ w_q, const float* __restrict__ w_bl,
           const float* __restrict__ w_k, const float* __restrict__ kin,
           const float* __restrict__ weight, float* __restrict__ ws,
           float* __restrict__ out) {
    int st = blockIdx.x, b = blockIdx.y;
    int tid = threadIdx.x;
    int lane = tid & 63, w = tid >> 6;

    if (st == 8) {
        // ---- corr final role: one block per b ----
        __shared__ float sF[Ssz];
        float wq3 = weight[b] * (1.f / 3.f);
        const float* n0 = ws + OFF_NORM + (size_t)(b * 3 + 0) * Ssz;
        const float* n1 = ws + OFF_NORM + (size_t)(b * 3 + 1) * Ssz;
        const float* n2 = ws + OFF_NORM + (size_t)(b * 3 + 2) * Ssz;
        #pragma unroll
        for (int j = 0; j < 4; ++j) {
            int q = tid + j * 1024;
            if (q < Ssz) {
                float s = n0[q] + n1[q] + n2[q];
                sF[q] = s;
                out[b * Ssz + q] = wq3 * s;
            }
        }
        __syncthreads();
        #pragma unroll
        for (int j = 0; j < 2; ++j) {
            int o = tid + j * 1024;
            if (o >= 1189) continue;
            int O, p, outi;
            if (o < 900)       { O = 30; p = o;        outi = 7200 + b * 900 + p; }
            else if (o < 1125) { O = 15; p = o - 900;  outi = 9000 + b * 225 + p; }
            else               { O = 8;  p = o - 1125; outi = 9450 + b * 64 + p; }
            int y = p / O, x = p - y * O;
            float sc = 59.f / (float)(O - 1);
            float py = y * sc, px = x * sc;
            int y0 = (int)floorf(py), x0 = (int)floorf(px);
            int y1 = min(y0 + 1, 59), x1 = min(x0 + 1, 59);
            float wy = py - y0, wx = px - x0;
            float v = sF[y0 * 60 + x0] * (1.f - wy) * (1.f - wx)
                    + sF[y1 * 60 + x0] * wy * (1.f - wx)
                    + sF[y0 * 60 + x1] * (1.f - wy) * wx
                    + sF[y1 * 60 + x1] * wy * wx;
            out[outi] = wq3 * v;
        }
        return;
    }

    // ---- u (computed redundantly per block; weights L3-hot) ----
    __shared__ float4 p4[16][64];
    __shared__ float qxs[256], qws[256], us[256];
    const float4* wq4 = (const float4*)w_q;
    const float4* wbl4 = (const float4*)w_bl;
    const float4* wk4 = (const float4*)w_k;

    float4 acc = {0.f, 0.f, 0.f, 0.f};
    #pragma unroll
    for (int j = 0; j < 35; ++j) {
        int e = w + 16 * j;
        if (e < TDIM + HID) {
            float x = (e < TDIM) ? text[b * TDIM + e] : proto[b * HID + e - TDIM];
            float4 f = wq4[(size_t)e * 64 + lane];
            acc.x += x * f.x; acc.y += x * f.y; acc.z += x * f.z; acc.w += x * f.w;
        }
    }
    p4[w][lane] = acc;
    __syncthreads();
    if (tid < 256) {
        const float* pf = (const float*)p4;
        float s = 0.f;
        #pragma unroll
        for (int ww = 0; ww < 16; ++ww) s += pf[ww * 256 + tid];
        qxs[tid] = s;
    }
    __syncthreads();

    acc.x = acc.y = acc.z = acc.w = 0.f;
    #pragma unroll
    for (int j = 0; j < 16; ++j) {
        int e = w + 16 * j;
        float x = qxs[e];
        float4 f = wbl4[(size_t)e * 64 + lane];
        acc.x += x * f.x; acc.y += x * f.y; acc.z += x * f.z; acc.w += x * f.w;
    }
    p4[w][lane] = acc;
    __syncthreads();
    if (tid < 256) {
        const float* pf = (const float*)p4;
        float s = 0.f;
        #pragma unroll
        for (int ww = 0; ww < 16; ++ww) s += pf[ww * 256 + tid];
        qws[tid] = s;
    }
    __syncthreads();

    acc.x = acc.y = acc.z = acc.w = 0.f;
    #pragma unroll
    for (int j = 0; j < 16; ++j) {
        int e = w + 16 * j;
        float x = qws[e];
        float4 f = wk4[(size_t)e * 64 + lane];
        acc.x += x * f.x; acc.y += x * f.y; acc.z += x * f.z; acc.w += x * f.w;
    }
    p4[w][lane] = acc;
    __syncthreads();
    if (tid < 256) {
        const float* pf = (const float*)p4;
        float s = 0.f;
        #pragma unroll
        for (int ww = 0; ww < 16; ++ww) s += pf[ww * 256 + tid];
        us[tid] = s;
    }
    __syncthreads();

    // ---- score strip: s = st*450 + tid (coalesced across lanes) ----
    if (tid < 450) {
        int s = st * 450 + tid;
        const float* kb = kin + (size_t)b * HID * Ssz + s;
        float a = 0.f;
        #pragma unroll 8
        for (int i = 0; i < HID; ++i) a += us[i] * kb[(size_t)i * Ssz];
        ws[OFF_SCORE + (size_t)b * Ssz + s] = a;
    }
}

// ---------------- kbar[b,i] = softmax(score) . k[b,i,:]  (softmax fused) ----
__global__ void k_kbar(const float* __restrict__ kin, float* __restrict__ ws) {
    int i = blockIdx.x, b = blockIdx.y;
    int tid = threadIdx.x;
    int lane = tid & 63, w = tid >> 6;
    __shared__ float r1[4], r2[4];
    const float4* s4 = (const float4*)(ws + OFF_SCORE + (size_t)b * Ssz);
    float4 sv[4]; bool act[4];
    float mx = -INFINITY;
    #pragma unroll
    for (int j = 0; j < 4; ++j) {
        int idx = tid + 256 * j;
        act[j] = idx < 900;
        if (act[j]) {
            float4 v = s4[idx];
            sv[j] = v;
            mx = fmaxf(mx, fmaxf(fmaxf(v.x, v.y), fmaxf(v.z, v.w)));
        }
    }
    #pragma unroll
    for (int m = 32; m >= 1; m >>= 1) mx = fmaxf(mx, __shfl_xor(mx, m, 64));
    if (lane == 0) r1[w] = mx;
    __syncthreads();
    mx = fmaxf(fmaxf(r1[0], r1[1]), fmaxf(r1[2], r1[3]));
    __syncthreads();
    const float4* kr = (const float4*)(kin + ((size_t)b * HID + i) * Ssz);
    float se = 0.f, wsum = 0.f;
    #pragma unroll
    for (int j = 0; j < 4; ++j) {
        if (act[j]) {
            int idx = tid + 256 * j;
            float4 v = sv[j];
            float ex = expf(v.x - mx), ey = expf(v.y - mx);
            float ez = expf(v.z - mx), ew = expf(v.w - mx);
            se += ex + ey + ez + ew;
            float4 k4 = kr[idx];
            wsum += ex * k4.x + ey * k4.y + ez * k4.z + ew * k4.w;
        }
    }
    #pragma unroll
    for (int m = 32; m >= 1; m >>= 1) {
        se += __shfl_xor(se, m, 64);
        wsum += __shfl_xor(wsum, m, 64);
    }
    if (lane == 0) { r1[w] = se; r2[w] = wsum; }
    __syncthreads();
    if (tid == 0) {
        float seT = r1[0] + r1[1] + r1[2] + r1[3];
        float wsT = r2[0] + r2[1] + r2[2] + r2[3];
        ws[OFF_KBAR + b * HID + i] = wsT / seT;
    }
}

// ---------------- out = w_proj^T (w_k kbar) + b + proto ---------------------
__global__ void __launch_bounds__(1024, 1)
k_apa_out(const float* __restrict__ w_k, const float* __restrict__ w_proj,
          const float* __restrict__ b_proj, const float* __restrict__ proto,
          const float* __restrict__ ws, float* __restrict__ out) {
    int b = blockIdx.x;
    int tid = threadIdx.x;
    int lane = tid & 63, w = tid >> 6;
    __shared__ float4 kbs[64];
    __shared__ float o1s[256];
    __shared__ float4 p4[16][64];
    const float4* wk4 = (const float4*)w_k;
    const float4* wp4 = (const float4*)w_proj;

    if (tid < 64) kbs[tid] = ((const float4*)(ws + OFF_KBAR + b * HID))[tid];
    __syncthreads();

    float4 kb4 = kbs[lane];
    #pragma unroll
    for (int r = 0; r < 16; ++r) {
        int h = w + 16 * r;
        float4 f = wk4[(size_t)h * 64 + lane];
        float p = f.x * kb4.x + f.y * kb4.y + f.z * kb4.z + f.w * kb4.w;
        #pragma unroll
        for (int m = 32; m >= 1; m >>= 1) p += __shfl_xor(p, m, 64);
        if (lane == 0) o1s[h] = p;
    }
    __syncthreads();

    float4 acc = {0.f, 0.f, 0.f, 0.f};
    #pragma unroll
    for (int j = 0; j < 16; ++j) {
        int d = w + 16 * j;
        float x = o1s[d];
        float4 f = wp4[(size_t)d * 64 + lane];
        acc.x += x * f.x; acc.y += x * f.y; acc.z += x * f.z; acc.w += x * f.w;
    }
    p4[w][lane] = acc;
    __syncthreads();
    if (tid < 256) {
        const float* pf = (const float*)p4;
        float s = 0.f;
        #pragma unroll
        for (int ww = 0; ww < 16; ++ww) s += pf[ww * 256 + tid];
        out[9578 + b * HID + tid] = s + b_proj[tid] + proto[b * HID + tid];
    }
}

extern "C" void kernel_launch(void* const* d_in, const int* in_sizes, int n_in,
                              void* d_out, int out_size, void* d_ws, size_t ws_size,
                              hipStream_t stream) {
    const float* weight = (const float*)d_in[0];
    const float* query  = (const float*)d_in[1];
    const float* supp   = (const float*)d_in[2];
    const float* masks  = (const float*)d_in[3];
    const float* kin    = (const float*)d_in[4];
    const float* text   = (const float*)d_in[5];
    const float* proto  = (const float*)d_in[6];
    const float* w_q    = (const float*)d_in[7];
    const float* w_k    = (const float*)d_in[8];
    const float* w_bl   = (const float*)d_in[9];
    const float* w_proj = (const float*)d_in[10];
    const float* b_proj = (const float*)d_in[11];
    float* out = (float*)d_out;
    float* ws  = (float*)d_ws;

    k_pool_sn2<<<dim3(4, 128, 2), 256, 0, stream>>>(supp, masks, ws);
    k_wmap<<<dim3(4, 6), 256, 0, stream>>>(masks, ws);
    k_v<<<dim3(256, 2), 256, 0, stream>>>(supp, ws);
    k_dot<<<dim3(15, 16, 2), 256, 0, stream>>>(query, ws);
    k_sim<<<6, 1024, 0, stream>>>(ws);
    k_apascore<<<dim3(9, 2), 1024, 0, stream>>>(text, proto, w_q, w_bl, w_k, kin,
                                                weight, ws, out);
    k_kbar<<<dim3(HID, 2), 256, 0, stream>>>(kin, ws);
    k_apa_out<<<Bsz, 1024, 0, stream>>>(w_k, w_proj, b_proj, proto, ws, out);
}

// Round 9
// 216.819 us; speedup vs baseline: 1.7581x; 1.1904x over previous
//
#include <hip/hip_runtime.h>
#include <math.h>

#define EPSF 1e-7f
#define Bsz 2
#define Cch 1024
#define Hh 60
#define Ssz 3600
#define HID 256
#define TDIM 300
#define MH 473

// pool tiling
#define TROWS 15
#define LROWS 21          // TROWS + 6 halo
#define LPITCH 68         // 4-col zero pad both sides of 60 cols
#define CPG 8             // channels per block (processed as 4 float2 pairs)

// workspace layout (float offsets) -- no counters, no zeroing needed
#define OFF_PPOOL  0               // 128*2*3*3600 pool partials (non-atomic)
#define OFF_WMAP   2764800         // 6*3600  mask-premultiplied pool(1/sn)
#define OFF_V      2786400         // 6*1024
#define OFF_DOTP   2792544         // 16*2*3*3600 dot partials
#define OFF_NORM   3138144         // 6*3600 normalized sim planes
#define OFF_SCORE  3159744         // 2*3600
#define OFF_KBAR   3166944         // 2*256

// ---------------- pass A: per-(cg,b) pool^2 partials (no atomics) ----------
__global__ void __launch_bounds__(256) k_pool_sn2(const float* __restrict__ supp,
                                                  const float* __restrict__ masks,
                                                  float* __restrict__ ws) {
    __shared__ float  mk[LROWS * LPITCH];
    __shared__ float2 raw[LROWS * LPITCH];
    __shared__ float2 h5s[LROWS * LPITCH];
    __shared__ float2 h7s[LROWS * LPITCH];
    int tid = threadIdx.x;
    int tile = blockIdx.x;       // 0..3
    int cg = blockIdx.y;         // 0..127
    int b = blockIdx.z;          // 0..1
    int y0 = tile * TROWS;

    const float2 z2 = {0.f, 0.f};
    for (int i = tid; i < LROWS * LPITCH; i += 256) {
        mk[i] = 0.f; raw[i] = z2; h5s[i] = z2; h7s[i] = z2;
    }
    __syncthreads();

    int lr[5], lx[5]; bool lv[5], la[5];
    #pragma unroll
    for (int j = 0; j < 5; ++j) {
        int idx = tid + 256 * j;
        int r = idx / 60, x = idx - 60 * r;
        lr[j] = r; lx[j] = x;
        la[j] = idx < 1260;
        int iy = y0 - 3 + r;
        lv[j] = la[j] && (iy >= 0) && (iy < Hh);
    }
    #pragma unroll
    for (int j = 0; j < 5; ++j)
        if (lv[j]) {
            int iy = y0 - 3 + lr[j];
            mk[lr[j] * LPITCH + 4 + lx[j]] =
                masks[(size_t)b * MH * MH + (size_t)(iy * 8) * MH + lx[j] * 8];
        }

    int orow[4], ox[4]; bool ov[4];
    #pragma unroll
    for (int j = 0; j < 4; ++j) {
        int o = tid + 256 * j;
        int oy = o / 60, x = o - 60 * oy;
        orow[j] = oy + 3; ox[j] = x; ov[j] = o < 900;
    }
    float a0[4] = {0,0,0,0}, a1[4] = {0,0,0,0}, a2[4] = {0,0,0,0};

    const float* chbase = supp + ((size_t)b * Cch + (size_t)cg * CPG) * Ssz + (y0 - 3) * 60;
    float pf0[5], pf1[5];
    #pragma unroll
    for (int j = 0; j < 5; ++j) {
        pf0[j] = lv[j] ? chbase[tid + 256 * j] : 0.f;
        pf1[j] = lv[j] ? chbase[Ssz + tid + 256 * j] : 0.f;
    }

    for (int p = 0; p < CPG / 2; ++p) {
        __syncthreads();
        #pragma unroll
        for (int j = 0; j < 5; ++j)
            if (lv[j]) {
                float m = mk[lr[j] * LPITCH + 4 + lx[j]];
                raw[lr[j] * LPITCH + 4 + lx[j]] = make_float2(pf0[j] * m, pf1[j] * m);
            }
        __syncthreads();
        #pragma unroll
        for (int j = 0; j < 5; ++j)
            if (la[j]) {
                int base = lr[j] * LPITCH + 4 + lx[j];
                float2 m3 = raw[base - 3], m2 = raw[base - 2], m1 = raw[base - 1];
                float2 c0 = raw[base], p1 = raw[base + 1], p2 = raw[base + 2], p3 = raw[base + 3];
                float2 h5, h7;
                h5.x = m2.x + m1.x + c0.x + p1.x + p2.x;
                h5.y = m2.y + m1.y + c0.y + p1.y + p2.y;
                h7.x = h5.x + m3.x + p3.x;
                h7.y = h5.y + m3.y + p3.y;
                h5s[base] = h5; h7s[base] = h7;
            }
        __syncthreads();
        if (p + 1 < CPG / 2) {
            const float* nb = chbase + (size_t)(2 * p + 2) * Ssz;
            #pragma unroll
            for (int j = 0; j < 5; ++j) {
                pf0[j] = lv[j] ? nb[tid + 256 * j] : 0.f;
                pf1[j] = lv[j] ? nb[Ssz + tid + 256 * j] : 0.f;
            }
        }
        #pragma unroll
        for (int j = 0; j < 4; ++j)
            if (ov[j]) {
                int base = orow[j] * LPITCH + 4 + ox[j];
                float2 sa = h5s[base - 2*LPITCH], sb = h5s[base - LPITCH], sc0 = h5s[base];
                float2 sd = h5s[base + LPITCH], se = h5s[base + 2*LPITCH];
                float p55x = (sa.x + sb.x + sc0.x + sd.x + se.x) * (1.f / 25.f);
                float p55y = (sa.y + sb.y + sc0.y + sd.y + se.y) * (1.f / 25.f);
                float2 ra = raw[base - 3*LPITCH], rb = raw[base - 2*LPITCH], rc = raw[base - LPITCH];
                float2 rd = raw[base], re = raw[base + LPITCH], rf = raw[base + 2*LPITCH], rg = raw[base + 3*LPITCH];
                float p71x = (ra.x + rb.x + rc.x + rd.x + re.x + rf.x + rg.x) * (1.f / 7.f);
                float p71y = (ra.y + rb.y + rc.y + rd.y + re.y + rf.y + rg.y) * (1.f / 7.f);
                float2 h7v = h7s[base];
                float p17x = h7v.x * (1.f / 7.f), p17y = h7v.y * (1.f / 7.f);
                a0[j] += p55x * p55x + p55y * p55y;
                a1[j] += p71x * p71x + p71y * p71y;
                a2[j] += p17x * p17x + p17y * p17y;
            }
    }
    float* dst = ws + OFF_PPOOL + (size_t)(cg * 2 + b) * 3 * Ssz;
    #pragma unroll
    for (int j = 0; j < 4; ++j)
        if (ov[j]) {
            int q = (y0 + orow[j] - 3) * 60 + ox[j];
            dst[q] = a0[j]; dst[Ssz + q] = a1[j]; dst[2 * Ssz + q] = a2[j];
        }
}

// ---------------- wm[b][kt] = mask * pool_kt(1/sqrt(sum partials)) ----------
// 1024 threads: partial summation with 4 independent accumulators fully
// unrolled -> ~32 loads in flight per thread (latency-tolerant).
__global__ void __launch_bounds__(1024) k_wmap(const float* __restrict__ masks,
                                               float* __restrict__ ws) {
    __shared__ float inv[LROWS * LPITCH];
    int tile = blockIdx.x;       // 0..3
    int bk = blockIdx.y;         // 0..5 = b*3+kt
    int b = bk / 3, kt = bk % 3;
    int tid = threadIdx.x;
    int y0 = tile * TROWS;
    for (int i = tid; i < LROWS * LPITCH; i += 1024) inv[i] = 0.f;
    __syncthreads();
    const float* pp = ws + OFF_PPOOL + (size_t)(b * 3 + kt) * Ssz;
    #pragma unroll
    for (int j = 0; j < 2; ++j) {
        int idx = tid + 1024 * j;
        if (idx < 1260) {
            int r = idx / 60, x = idx - 60 * r;
            int iy = y0 - 3 + r;
            if (iy >= 0 && iy < Hh) {
                int q = iy * 60 + x;
                float s0 = 0.f, s1 = 0.f, s2 = 0.f, s3 = 0.f;
                #pragma unroll
                for (int g = 0; g < 128; g += 4) {
                    s0 += pp[(size_t)(g + 0) * (6 * Ssz) + q];
                    s1 += pp[(size_t)(g + 1) * (6 * Ssz) + q];
                    s2 += pp[(size_t)(g + 2) * (6 * Ssz) + q];
                    s3 += pp[(size_t)(g + 3) * (6 * Ssz) + q];
                }
                float s = (s0 + s1) + (s2 + s3);
                inv[r * LPITCH + 4 + x] = 1.0f / sqrtf(fmaxf(s, 1e-30f));
            }
        }
    }
    __syncthreads();
    int kh = (kt == 0) ? 5 : (kt == 1) ? 7 : 1;
    int kw = (kt == 0) ? 5 : (kt == 2) ? 7 : 1;
    int rh = kh / 2, rw = kw / 2;
    float norm = 1.f / (float)(kh * kw);
    int o = tid;
    if (o < 900) {
        int oy = o / 60, x = o - 60 * oy;
        int base = (oy + 3) * LPITCH + 4 + x;
        float s = 0.f;
        for (int dy = -rh; dy <= rh; ++dy)
            for (int dx = -rw; dx <= rw; ++dx)
                s += inv[base + dy * LPITCH + dx];
        int gy = y0 + oy;
        float m = masks[(size_t)b * MH * MH + (size_t)(gy * 8) * MH + x * 8];
        ws[OFF_WMAP + (size_t)bk * Ssz + gy * 60 + x] = s * norm * m;
    }
}

// ---------------- v[b][kt][c] : 4 channels/block, wmap reused ---------------
__global__ void k_v(const float* __restrict__ supp, float* __restrict__ ws) {
    int cB = blockIdx.x, b = blockIdx.y;
    int tid = threadIdx.x, lane = tid & 63, w = tid >> 6;
    int c0 = cB * 4;
    const float4* sp4 = (const float4*)(supp + ((size_t)b * Cch + c0) * Ssz);
    const float4* w04 = (const float4*)(ws + OFF_WMAP + (size_t)(b * 3 + 0) * Ssz);
    const float4* w14 = (const float4*)(ws + OFF_WMAP + (size_t)(b * 3 + 1) * Ssz);
    const float4* w24 = (const float4*)(ws + OFF_WMAP + (size_t)(b * 3 + 2) * Ssz);
    float a[4][3];
    #pragma unroll
    for (int cc = 0; cc < 4; ++cc) { a[cc][0] = 0; a[cc][1] = 0; a[cc][2] = 0; }
    #pragma unroll
    for (int j = 0; j < 4; ++j) {
        int idx = tid + 256 * j;
        if (idx < 900) {
            float4 g0 = w04[idx], g1 = w14[idx], g2 = w24[idx];
            #pragma unroll
            for (int cc = 0; cc < 4; ++cc) {
                float4 f = sp4[cc * 900 + idx];
                a[cc][0] += f.x * g0.x + f.y * g0.y + f.z * g0.z + f.w * g0.w;
                a[cc][1] += f.x * g1.x + f.y * g1.y + f.z * g1.z + f.w * g1.w;
                a[cc][2] += f.x * g2.x + f.y * g2.y + f.z * g2.z + f.w * g2.w;
            }
        }
    }
    #pragma unroll
    for (int m = 32; m >= 1; m >>= 1)
        #pragma unroll
        for (int cc = 0; cc < 4; ++cc) {
            a[cc][0] += __shfl_xor(a[cc][0], m, 64);
            a[cc][1] += __shfl_xor(a[cc][1], m, 64);
            a[cc][2] += __shfl_xor(a[cc][2], m, 64);
        }
    __shared__ float r[4][3][4];
    if (lane == 0)
        #pragma unroll
        for (int cc = 0; cc < 4; ++cc) {
            r[cc][0][w] = a[cc][0]; r[cc][1][w] = a[cc][1]; r[cc][2][w] = a[cc][2];
        }
    __syncthreads();
    if (tid < 12) {
        int cc = tid / 3, kk = tid - cc * 3;
        float s = r[cc][kk][0] + r[cc][kk][1] + r[cc][kk][2] + r[cc][kk][3];
        ws[OFF_V + (size_t)(b * 3 + kk) * Cch + c0 + cc] = s;
    }
}

// ---------------- dotp[cc][b][kt][q] = sum_{c in cc} query[c,q]*v[kt][c] ----
__global__ void k_dot(const float* __restrict__ query, float* __restrict__ ws) {
    int qt = blockIdx.x, cc = blockIdx.y, b = blockIdx.z;
    int q = qt * 256 + threadIdx.x;
    if (q >= Ssz) return;
    const float* v0 = ws + OFF_V + (size_t)(b * 3 + 0) * Cch;
    const float* v1 = ws + OFF_V + (size_t)(b * 3 + 1) * Cch;
    const float* v2 = ws + OFF_V + (size_t)(b * 3 + 2) * Cch;
    float a0 = 0, a1 = 0, a2 = 0;
    int c0 = cc * 64;
    #pragma unroll 8
    for (int c = c0; c < c0 + 64; ++c) {
        float qv = query[((size_t)b * Cch + c) * Ssz + q];
        a0 += qv * v0[c]; a1 += qv * v1[c]; a2 += qv * v2[c];
    }
    float* dst = ws + OFF_DOTP + (size_t)((cc * 2 + b) * 3) * Ssz + q;
    dst[0] = a0; dst[Ssz] = a1; dst[2 * Ssz] = a2;
}

// ---------------- sim: sum partials, pool, minmax-norm -> NORM planes -------
__global__ void __launch_bounds__(1024) k_sim(float* __restrict__ ws) {
    __shared__ float sA[66 * LPITCH];
    __shared__ float sB[66 * LPITCH];
    __shared__ float rmin[16], rmax[16];
    int bk = blockIdx.x; int b = bk / 3; int kt = bk % 3;
    int tid = threadIdx.x;
    int lane = tid & 63, w = tid >> 6;

    const float* dp0 = ws + OFF_DOTP + (size_t)(b * 3 + kt) * Ssz;
    for (int i = tid; i < 66 * LPITCH; i += 1024) {
        int r = i / LPITCH, col = i - r * LPITCH;
        int y = r - 3, x = col - 4;
        float s = 0.f;
        if (y >= 0 && y < Hh && x >= 0 && x < Hh) {
            int q = y * Hh + x;
            #pragma unroll
            for (int g = 0; g < 16; ++g) s += dp0[(size_t)g * 6 * Ssz + q];
        }
        sA[i] = s;
    }
    __syncthreads();
    if (kt != 1) {
        for (int idx = tid; idx < 66 * 60; idx += 1024) {
            int r = idx / 60, x = idx - 60 * r;
            int base = r * LPITCH + 4 + x;
            if (kt == 0)
                sB[base] = sA[base - 2] + sA[base - 1] + sA[base] + sA[base + 1] + sA[base + 2];
            else
                sB[base] = sA[base - 3] + sA[base - 2] + sA[base - 1] + sA[base]
                         + sA[base + 1] + sA[base + 2] + sA[base + 3];
        }
    }
    __syncthreads();
    float norm = ((kt == 0) ? (1.f / 25.f) : (1.f / 7.f)) * (1.f / (float)Ssz);
    float vals[4];
    float vmin = INFINITY, vmax = -INFINITY;
    #pragma unroll
    for (int j = 0; j < 4; ++j) {
        int q = tid + j * 1024;
        if (q < Ssz) {
            int y = q / Hh, x = q - y * Hh;
            int base = (y + 3) * LPITCH + 4 + x;
            float s;
            if (kt == 0)
                s = sB[base - 2*LPITCH] + sB[base - LPITCH] + sB[base]
                  + sB[base + LPITCH] + sB[base + 2*LPITCH];
            else if (kt == 1)
                s = sA[base - 3*LPITCH] + sA[base - 2*LPITCH] + sA[base - LPITCH]
                  + sA[base] + sA[base + LPITCH] + sA[base + 2*LPITCH] + sA[base + 3*LPITCH];
            else
                s = sB[base];
            float val = s * norm;
            vals[j] = val;
            vmin = fminf(vmin, val); vmax = fmaxf(vmax, val);
        }
    }
    #pragma unroll
    for (int m = 32; m >= 1; m >>= 1) {
        vmin = fminf(vmin, __shfl_xor(vmin, m, 64));
        vmax = fmaxf(vmax, __shfl_xor(vmax, m, 64));
    }
    if (lane == 0) { rmin[w] = vmin; rmax[w] = vmax; }
    __syncthreads();
    float mn = rmin[0], mx = rmax[0];
    #pragma unroll
    for (int ww = 1; ww < 16; ++ww) {
        mn = fminf(mn, rmin[ww]); mx = fmaxf(mx, rmax[ww]);
    }
    float inv = 1.f / (mx - mn + EPSF);
    float* np = ws + OFF_NORM + (size_t)(b * 3 + kt) * Ssz;
    #pragma unroll
    for (int j = 0; j < 4; ++j) {
        int q = tid + j * 1024;
        if (q < Ssz) np[q] = (vals[j] - mn) * inv;
    }
}

// ---------------- APA u + score strips, plus corr-final role (st==8) --------
__global__ void __launch_bounds__(1024, 1)
k_apascore(const float* __restrict__ text, const float* __restrict__ proto,
           const float* __restrict__ w_q, const float* __restrict__ w_bl,
           const float* __restrict__ w_k, const float* __restrict__ kin,
           const float* __restrict__ weight, float* __restrict__ ws,
           float* __restrict__ out) {
    int st = blockIdx.x, b = blockIdx.y;
    int tid = threadIdx.x;
    int lane = tid & 63, w = tid >> 6;

    if (st == 8) {
        // ---- corr final role: one block per b ----
        __shared__ float sF[Ssz];
        float wq3 = weight[b] * (1.f / 3.f);
        const float* n0 = ws + OFF_NORM + (size_t)(b * 3 + 0) * Ssz;
        const float* n1 = ws + OFF_NORM + (size_t)(b * 3 + 1) * Ssz;
        const float* n2 = ws + OFF_NORM + (size_t)(b * 3 + 2) * Ssz;
        #pragma unroll
        for (int j = 0; j < 4; ++j) {
            int q = tid + j * 1024;
            if (q < Ssz) {
                float s = n0[q] + n1[q] + n2[q];
                sF[q] = s;
                out[b * Ssz + q] = wq3 * s;
            }
        }
        __syncthreads();
        #pragma unroll
        for (int j = 0; j < 2; ++j) {
            int o = tid + j * 1024;
            if (o >= 1189) continue;
            int O, p, outi;
            if (o < 900)       { O = 30; p = o;        outi = 7200 + b * 900 + p; }
            else if (o < 1125) { O = 15; p = o - 900;  outi = 9000 + b * 225 + p; }
            else               { O = 8;  p = o - 1125; outi = 9450 + b * 64 + p; }
            int y = p / O, x = p - y * O;
            float sc = 59.f / (float)(O - 1);
            float py = y * sc, px = x * sc;
            int y0 = (int)floorf(py), x0 = (int)floorf(px);
            int y1 = min(y0 + 1, 59), x1 = min(x0 + 1, 59);
            float wy = py - y0, wx = px - x0;
            float v = sF[y0 * 60 + x0] * (1.f - wy) * (1.f - wx)
                    + sF[y1 * 60 + x0] * wy * (1.f - wx)
                    + sF[y0 * 60 + x1] * (1.f - wy) * wx
                    + sF[y1 * 60 + x1] * wy * wx;
            out[outi] = wq3 * v;
        }
        return;
    }

    // ---- u (computed redundantly per block; weights L3-hot) ----
    __shared__ float4 p4[16][64];
    __shared__ float qxs[256], qws[256], us[256];
    const float4* wq4 = (const float4*)w_q;
    const float4* wbl4 = (const float4*)w_bl;
    const float4* wk4 = (const float4*)w_k;

    float4 acc = {0.f, 0.f, 0.f, 0.f};
    #pragma unroll
    for (int j = 0; j < 35; ++j) {
        int e = w + 16 * j;
        if (e < TDIM + HID) {
            float x = (e < TDIM) ? text[b * TDIM + e] : proto[b * HID + e - TDIM];
            float4 f = wq4[(size_t)e * 64 + lane];
            acc.x += x * f.x; acc.y += x * f.y; acc.z += x * f.z; acc.w += x * f.w;
        }
    }
    p4[w][lane] = acc;
    __syncthreads();
    if (tid < 256) {
        const float* pf = (const float*)p4;
        float s = 0.f;
        #pragma unroll
        for (int ww = 0; ww < 16; ++ww) s += pf[ww * 256 + tid];
        qxs[tid] = s;
    }
    __syncthreads();

    acc.x = acc.y = acc.z = acc.w = 0.f;
    #pragma unroll
    for (int j = 0; j < 16; ++j) {
        int e = w + 16 * j;
        float x = qxs[e];
        float4 f = wbl4[(size_t)e * 64 + lane];
        acc.x += x * f.x; acc.y += x * f.y; acc.z += x * f.z; acc.w += x * f.w;
    }
    p4[w][lane] = acc;
    __syncthreads();
    if (tid < 256) {
        const float* pf = (const float*)p4;
        float s = 0.f;
        #pragma unroll
        for (int ww = 0; ww < 16; ++ww) s += pf[ww * 256 + tid];
        qws[tid] = s;
    }
    __syncthreads();

    acc.x = acc.y = acc.z = acc.w = 0.f;
    #pragma unroll
    for (int j = 0; j < 16; ++j) {
        int e = w + 16 * j;
        float x = qws[e];
        float4 f = wk4[(size_t)e * 64 + lane];
        acc.x += x * f.x; acc.y += x * f.y; acc.z += x * f.z; acc.w += x * f.w;
    }
    p4[w][lane] = acc;
    __syncthreads();
    if (tid < 256) {
        const float* pf = (const float*)p4;
        float s = 0.f;
        #pragma unroll
        for (int ww = 0; ww < 16; ++ww) s += pf[ww * 256 + tid];
        us[tid] = s;
    }
    __syncthreads();

    // ---- score strip: s = st*450 + tid (coalesced across lanes) ----
    if (tid < 450) {
        int s = st * 450 + tid;
        const float* kb = kin + (size_t)b * HID * Ssz + s;
        float a = 0.f;
        #pragma unroll 8
        for (int i = 0; i < HID; ++i) a += us[i] * kb[(size_t)i * Ssz];
        ws[OFF_SCORE + (size_t)b * Ssz + s] = a;
    }
}

// ---------------- kbar[b,i] = softmax(score) . k[b,i,:]  (softmax fused) ----
__global__ void k_kbar(const float* __restrict__ kin, float* __restrict__ ws) {
    int i = blockIdx.x, b = blockIdx.y;
    int tid = threadIdx.x;
    int lane = tid & 63, w = tid >> 6;
    __shared__ float r1[4], r2[4];
    const float4* s4 = (const float4*)(ws + OFF_SCORE + (size_t)b * Ssz);
    float4 sv[4]; bool act[4];
    float mx = -INFINITY;
    #pragma unroll
    for (int j = 0; j < 4; ++j) {
        int idx = tid + 256 * j;
        act[j] = idx < 900;
        if (act[j]) {
            float4 v = s4[idx];
            sv[j] = v;
            mx = fmaxf(mx, fmaxf(fmaxf(v.x, v.y), fmaxf(v.z, v.w)));
        }
    }
    #pragma unroll
    for (int m = 32; m >= 1; m >>= 1) mx = fmaxf(mx, __shfl_xor(mx, m, 64));
    if (lane == 0) r1[w] = mx;
    __syncthreads();
    mx = fmaxf(fmaxf(r1[0], r1[1]), fmaxf(r1[2], r1[3]));
    __syncthreads();
    const float4* kr = (const float4*)(kin + ((size_t)b * HID + i) * Ssz);
    float se = 0.f, wsum = 0.f;
    #pragma unroll
    for (int j = 0; j < 4; ++j) {
        if (act[j]) {
            int idx = tid + 256 * j;
            float4 v = sv[j];
            float ex = expf(v.x - mx), ey = expf(v.y - mx);
            float ez = expf(v.z - mx), ew = expf(v.w - mx);
            se += ex + ey + ez + ew;
            float4 k4 = kr[idx];
            wsum += ex * k4.x + ey * k4.y + ez * k4.z + ew * k4.w;
        }
    }
    #pragma unroll
    for (int m = 32; m >= 1; m >>= 1) {
        se += __shfl_xor(se, m, 64);
        wsum += __shfl_xor(wsum, m, 64);
    }
    if (lane == 0) { r1[w] = se; r2[w] = wsum; }
    __syncthreads();
    if (tid == 0) {
        float seT = r1[0] + r1[1] + r1[2] + r1[3];
        float wsT = r2[0] + r2[1] + r2[2] + r2[3];
        ws[OFF_KBAR + b * HID + i] = wsT / seT;
    }
}

// ---------------- out = w_proj^T (w_k kbar) + b + proto ---------------------
__global__ void __launch_bounds__(1024, 1)
k_apa_out(const float* __restrict__ w_k, const float* __restrict__ w_proj,
          const float* __restrict__ b_proj, const float* __restrict__ proto,
          const float* __restrict__ ws, float* __restrict__ out) {
    int b = blockIdx.x;
    int tid = threadIdx.x;
    int lane = tid & 63, w = tid >> 6;
    __shared__ float4 kbs[64];
    __shared__ float o1s[256];
    __shared__ float4 p4[16][64];
    const float4* wk4 = (const float4*)w_k;
    const float4* wp4 = (const float4*)w_proj;

    if (tid < 64) kbs[tid] = ((const float4*)(ws + OFF_KBAR + b * HID))[tid];
    __syncthreads();

    float4 kb4 = kbs[lane];
    #pragma unroll
    for (int r = 0; r < 16; ++r) {
        int h = w + 16 * r;
        float4 f = wk4[(size_t)h * 64 + lane];
        float p = f.x * kb4.x + f.y * kb4.y + f.z * kb4.z + f.w * kb4.w;
        #pragma unroll
        for (int m = 32; m >= 1; m >>= 1) p += __shfl_xor(p, m, 64);
        if (lane == 0) o1s[h] = p;
    }
    __syncthreads();

    float4 acc = {0.f, 0.f, 0.f, 0.f};
    #pragma unroll
    for (int j = 0; j < 16; ++j) {
        int d = w + 16 * j;
        float x = o1s[d];
        float4 f = wp4[(size_t)d * 64 + lane];
        acc.x += x * f.x; acc.y += x * f.y; acc.z += x * f.z; acc.w += x * f.w;
    }
    p4[w][lane] = acc;
    __syncthreads();
    if (tid < 256) {
        const float* pf = (const float*)p4;
        float s = 0.f;
        #pragma unroll
        for (int ww = 0; ww < 16; ++ww) s += pf[ww * 256 + tid];
        out[9578 + b * HID + tid] = s + b_proj[tid] + proto[b * HID + tid];
    }
}

extern "C" void kernel_launch(void* const* d_in, const int* in_sizes, int n_in,
                              void* d_out, int out_size, void* d_ws, size_t ws_size,
                              hipStream_t stream) {
    const float* weight = (const float*)d_in[0];
    const float* query  = (const float*)d_in[1];
    const float* supp   = (const float*)d_in[2];
    const float* masks  = (const float*)d_in[3];
    const float* kin    = (const float*)d_in[4];
    const float* text   = (const float*)d_in[5];
    const float* proto  = (const float*)d_in[6];
    const float* w_q    = (const float*)d_in[7];
    const float* w_k    = (const float*)d_in[8];
    const float* w_bl   = (const float*)d_in[9];
    const float* w_proj = (const float*)d_in[10];
    const float* b_proj = (const float*)d_in[11];
    float* out = (float*)d_out;
    float* ws  = (float*)d_ws;

    k_pool_sn2<<<dim3(4, 128, 2), 256, 0, stream>>>(supp, masks, ws);
    k_wmap<<<dim3(4, 6), 1024, 0, stream>>>(masks, ws);
    k_v<<<dim3(256, 2), 256, 0, stream>>>(supp, ws);
    k_dot<<<dim3(15, 16, 2), 256, 0, stream>>>(query, ws);
    k_sim<<<6, 1024, 0, stream>>>(ws);
    k_apascore<<<dim3(9, 2), 1024, 0, stream>>>(text, proto, w_q, w_bl, w_k, kin,
                                                weight, ws, out);
    k_kbar<<<dim3(HID, 2), 256, 0, stream>>>(kin, ws);
    k_apa_out<<<Bsz, 1024, 0, stream>>>(w_k, w_proj, b_proj, proto, ws, out);
}

// Round 10
// 205.566 us; speedup vs baseline: 1.8543x; 1.0547x over previous
//
#include <hip/hip_runtime.h>
#include <math.h>

#define EPSF 1e-7f
#define Bsz 2
#define Cch 1024
#define Hh 60
#define Ssz 3600
#define HID 256
#define TDIM 300
#define MH 473

// pool tiling
#define TROWS 15
#define LROWS 21          // TROWS + 6 halo
#define LPITCH 68         // 4-col zero pad both sides of 60 cols
#define CPG 8             // channels per block (processed as 4 float2 pairs)

// workspace layout (float offsets) -- no counters, no zeroing needed
#define OFF_PPOOL  0               // 128*2*3*3600 pool partials (non-atomic)
#define OFF_WMAP   2764800         // 6*3600  mask-premultiplied pool(1/sn)
#define OFF_V      2786400         // 6*1024
#define OFF_DOTP   2792544         // 16*2*3*3600 dot partials
#define OFF_NORM   3138144         // 6*3600 normalized sim planes
#define OFF_SCORE  3159744         // 2*3600
#define OFF_KBAR   3166944         // 2*256
#define OFF_U      3167456         // 2*256

// ---------------- pass A: per-(cg,b) pool^2 partials (no atomics) ----------
__global__ void __launch_bounds__(256) k_pool_sn2(const float* __restrict__ supp,
                                                  const float* __restrict__ masks,
                                                  float* __restrict__ ws) {
    __shared__ float  mk[LROWS * LPITCH];
    __shared__ float2 raw[LROWS * LPITCH];
    __shared__ float2 h5s[LROWS * LPITCH];
    __shared__ float2 h7s[LROWS * LPITCH];
    int tid = threadIdx.x;
    int tile = blockIdx.x;       // 0..3
    int cg = blockIdx.y;         // 0..127
    int b = blockIdx.z;          // 0..1
    int y0 = tile * TROWS;

    const float2 z2 = {0.f, 0.f};
    for (int i = tid; i < LROWS * LPITCH; i += 256) {
        mk[i] = 0.f; raw[i] = z2; h5s[i] = z2; h7s[i] = z2;
    }
    __syncthreads();

    int lr[5], lx[5]; bool lv[5], la[5];
    #pragma unroll
    for (int j = 0; j < 5; ++j) {
        int idx = tid + 256 * j;
        int r = idx / 60, x = idx - 60 * r;
        lr[j] = r; lx[j] = x;
        la[j] = idx < 1260;
        int iy = y0 - 3 + r;
        lv[j] = la[j] && (iy >= 0) && (iy < Hh);
    }
    #pragma unroll
    for (int j = 0; j < 5; ++j)
        if (lv[j]) {
            int iy = y0 - 3 + lr[j];
            mk[lr[j] * LPITCH + 4 + lx[j]] =
                masks[(size_t)b * MH * MH + (size_t)(iy * 8) * MH + lx[j] * 8];
        }

    int orow[4], ox[4]; bool ov[4];
    #pragma unroll
    for (int j = 0; j < 4; ++j) {
        int o = tid + 256 * j;
        int oy = o / 60, x = o - 60 * oy;
        orow[j] = oy + 3; ox[j] = x; ov[j] = o < 900;
    }
    float a0[4] = {0,0,0,0}, a1[4] = {0,0,0,0}, a2[4] = {0,0,0,0};

    const float* chbase = supp + ((size_t)b * Cch + (size_t)cg * CPG) * Ssz + (y0 - 3) * 60;
    float pf0[5], pf1[5];
    #pragma unroll
    for (int j = 0; j < 5; ++j) {
        pf0[j] = lv[j] ? chbase[tid + 256 * j] : 0.f;
        pf1[j] = lv[j] ? chbase[Ssz + tid + 256 * j] : 0.f;
    }

    for (int p = 0; p < CPG / 2; ++p) {
        __syncthreads();
        #pragma unroll
        for (int j = 0; j < 5; ++j)
            if (lv[j]) {
                float m = mk[lr[j] * LPITCH + 4 + lx[j]];
                raw[lr[j] * LPITCH + 4 + lx[j]] = make_float2(pf0[j] * m, pf1[j] * m);
            }
        __syncthreads();
        #pragma unroll
        for (int j = 0; j < 5; ++j)
            if (la[j]) {
                int base = lr[j] * LPITCH + 4 + lx[j];
                float2 m3 = raw[base - 3], m2 = raw[base - 2], m1 = raw[base - 1];
                float2 c0 = raw[base], p1 = raw[base + 1], p2 = raw[base + 2], p3 = raw[base + 3];
                float2 h5, h7;
                h5.x = m2.x + m1.x + c0.x + p1.x + p2.x;
                h5.y = m2.y + m1.y + c0.y + p1.y + p2.y;
                h7.x = h5.x + m3.x + p3.x;
                h7.y = h5.y + m3.y + p3.y;
                h5s[base] = h5; h7s[base] = h7;
            }
        __syncthreads();
        if (p + 1 < CPG / 2) {
            const float* nb = chbase + (size_t)(2 * p + 2) * Ssz;
            #pragma unroll
            for (int j = 0; j < 5; ++j) {
                pf0[j] = lv[j] ? nb[tid + 256 * j] : 0.f;
                pf1[j] = lv[j] ? nb[Ssz + tid + 256 * j] : 0.f;
            }
        }
        #pragma unroll
        for (int j = 0; j < 4; ++j)
            if (ov[j]) {
                int base = orow[j] * LPITCH + 4 + ox[j];
                float2 sa = h5s[base - 2*LPITCH], sb = h5s[base - LPITCH], sc0 = h5s[base];
                float2 sd = h5s[base + LPITCH], se = h5s[base + 2*LPITCH];
                float p55x = (sa.x + sb.x + sc0.x + sd.x + se.x) * (1.f / 25.f);
                float p55y = (sa.y + sb.y + sc0.y + sd.y + se.y) * (1.f / 25.f);
                float2 ra = raw[base - 3*LPITCH], rb = raw[base - 2*LPITCH], rc = raw[base - LPITCH];
                float2 rd = raw[base], re = raw[base + LPITCH], rf = raw[base + 2*LPITCH], rg = raw[base + 3*LPITCH];
                float p71x = (ra.x + rb.x + rc.x + rd.x + re.x + rf.x + rg.x) * (1.f / 7.f);
                float p71y = (ra.y + rb.y + rc.y + rd.y + re.y + rf.y + rg.y) * (1.f / 7.f);
                float2 h7v = h7s[base];
                float p17x = h7v.x * (1.f / 7.f), p17y = h7v.y * (1.f / 7.f);
                a0[j] += p55x * p55x + p55y * p55y;
                a1[j] += p71x * p71x + p71y * p71y;
                a2[j] += p17x * p17x + p17y * p17y;
            }
    }
    float* dst = ws + OFF_PPOOL + (size_t)(cg * 2 + b) * 3 * Ssz;
    #pragma unroll
    for (int j = 0; j < 4; ++j)
        if (ov[j]) {
            int q = (y0 + orow[j] - 3) * 60 + ox[j];
            dst[q] = a0[j]; dst[Ssz + q] = a1[j]; dst[2 * Ssz + q] = a2[j];
        }
}

// ---------------- wm[b][kt] = mask * pool_kt(1/sqrt(sum partials)) ----------
__global__ void __launch_bounds__(1024) k_wmap(const float* __restrict__ masks,
                                               float* __restrict__ ws) {
    __shared__ float inv[LROWS * LPITCH];
    int tile = blockIdx.x;       // 0..3
    int bk = blockIdx.y;         // 0..5 = b*3+kt
    int b = bk / 3, kt = bk % 3;
    int tid = threadIdx.x;
    int y0 = tile * TROWS;
    for (int i = tid; i < LROWS * LPITCH; i += 1024) inv[i] = 0.f;
    __syncthreads();
    const float* pp = ws + OFF_PPOOL + (size_t)(b * 3 + kt) * Ssz;
    #pragma unroll
    for (int j = 0; j < 2; ++j) {
        int idx = tid + 1024 * j;
        if (idx < 1260) {
            int r = idx / 60, x = idx - 60 * r;
            int iy = y0 - 3 + r;
            if (iy >= 0 && iy < Hh) {
                int q = iy * 60 + x;
                float s0 = 0.f, s1 = 0.f, s2 = 0.f, s3 = 0.f;
                #pragma unroll
                for (int g = 0; g < 128; g += 4) {
                    s0 += pp[(size_t)(g + 0) * (6 * Ssz) + q];
                    s1 += pp[(size_t)(g + 1) * (6 * Ssz) + q];
                    s2 += pp[(size_t)(g + 2) * (6 * Ssz) + q];
                    s3 += pp[(size_t)(g + 3) * (6 * Ssz) + q];
                }
                float s = (s0 + s1) + (s2 + s3);
                inv[r * LPITCH + 4 + x] = 1.0f / sqrtf(fmaxf(s, 1e-30f));
            }
        }
    }
    __syncthreads();
    int kh = (kt == 0) ? 5 : (kt == 1) ? 7 : 1;
    int kw = (kt == 0) ? 5 : (kt == 2) ? 7 : 1;
    int rh = kh / 2, rw = kw / 2;
    float norm = 1.f / (float)(kh * kw);
    int o = tid;
    if (o < 900) {
        int oy = o / 60, x = o - 60 * oy;
        int base = (oy + 3) * LPITCH + 4 + x;
        float s = 0.f;
        for (int dy = -rh; dy <= rh; ++dy)
            for (int dx = -rw; dx <= rw; ++dx)
                s += inv[base + dy * LPITCH + dx];
        int gy = y0 + oy;
        float m = masks[(size_t)b * MH * MH + (size_t)(gy * 8) * MH + x * 8];
        ws[OFF_WMAP + (size_t)bk * Ssz + gy * 60 + x] = s * norm * m;
    }
}

// ---------------- v[b][kt][c] : 4 channels/block, wmap reused ---------------
__global__ void k_v(const float* __restrict__ supp, float* __restrict__ ws) {
    int cB = blockIdx.x, b = blockIdx.y;
    int tid = threadIdx.x, lane = tid & 63, w = tid >> 6;
    int c0 = cB * 4;
    const float4* sp4 = (const float4*)(supp + ((size_t)b * Cch + c0) * Ssz);
    const float4* w04 = (const float4*)(ws + OFF_WMAP + (size_t)(b * 3 + 0) * Ssz);
    const float4* w14 = (const float4*)(ws + OFF_WMAP + (size_t)(b * 3 + 1) * Ssz);
    const float4* w24 = (const float4*)(ws + OFF_WMAP + (size_t)(b * 3 + 2) * Ssz);
    float a[4][3];
    #pragma unroll
    for (int cc = 0; cc < 4; ++cc) { a[cc][0] = 0; a[cc][1] = 0; a[cc][2] = 0; }
    #pragma unroll
    for (int j = 0; j < 4; ++j) {
        int idx = tid + 256 * j;
        if (idx < 900) {
            float4 g0 = w04[idx], g1 = w14[idx], g2 = w24[idx];
            #pragma unroll
            for (int cc = 0; cc < 4; ++cc) {
                float4 f = sp4[cc * 900 + idx];
                a[cc][0] += f.x * g0.x + f.y * g0.y + f.z * g0.z + f.w * g0.w;
                a[cc][1] += f.x * g1.x + f.y * g1.y + f.z * g1.z + f.w * g1.w;
                a[cc][2] += f.x * g2.x + f.y * g2.y + f.z * g2.z + f.w * g2.w;
            }
        }
    }
    #pragma unroll
    for (int m = 32; m >= 1; m >>= 1)
        #pragma unroll
        for (int cc = 0; cc < 4; ++cc) {
            a[cc][0] += __shfl_xor(a[cc][0], m, 64);
            a[cc][1] += __shfl_xor(a[cc][1], m, 64);
            a[cc][2] += __shfl_xor(a[cc][2], m, 64);
        }
    __shared__ float r[4][3][4];
    if (lane == 0)
        #pragma unroll
        for (int cc = 0; cc < 4; ++cc) {
            r[cc][0][w] = a[cc][0]; r[cc][1][w] = a[cc][1]; r[cc][2][w] = a[cc][2];
        }
    __syncthreads();
    if (tid < 12) {
        int cc = tid / 3, kk = tid - cc * 3;
        float s = r[cc][kk][0] + r[cc][kk][1] + r[cc][kk][2] + r[cc][kk][3];
        ws[OFF_V + (size_t)(b * 3 + kk) * Cch + c0 + cc] = s;
    }
}

// ---------------- dotp[cc][b][kt][q] = sum_{c in cc} query[c,q]*v[kt][c] ----
__global__ void k_dot(const float* __restrict__ query, float* __restrict__ ws) {
    int qt = blockIdx.x, cc = blockIdx.y, b = blockIdx.z;
    int q = qt * 256 + threadIdx.x;
    if (q >= Ssz) return;
    const float* v0 = ws + OFF_V + (size_t)(b * 3 + 0) * Cch;
    const float* v1 = ws + OFF_V + (size_t)(b * 3 + 1) * Cch;
    const float* v2 = ws + OFF_V + (size_t)(b * 3 + 2) * Cch;
    float a0 = 0, a1 = 0, a2 = 0;
    int c0 = cc * 64;
    #pragma unroll 8
    for (int c = c0; c < c0 + 64; ++c) {
        float qv = query[((size_t)b * Cch + c) * Ssz + q];
        a0 += qv * v0[c]; a1 += qv * v1[c]; a2 += qv * v2[c];
    }
    float* dst = ws + OFF_DOTP + (size_t)((cc * 2 + b) * 3) * Ssz + q;
    dst[0] = a0; dst[Ssz] = a1; dst[2 * Ssz] = a2;
}

// ---------------- sim (bk 0..5) + APA-u role (bk 6..7) ----------------------
__global__ void __launch_bounds__(1024) k_sim(const float* __restrict__ text,
                                              const float* __restrict__ proto,
                                              const float* __restrict__ w_q,
                                              const float* __restrict__ w_bl,
                                              const float* __restrict__ w_k,
                                              float* __restrict__ ws) {
    int bkx = blockIdx.x;
    int tid = threadIdx.x;
    int lane = tid & 63, w = tid >> 6;

    if (bkx >= 6) {
        // ---- u role: u = w_k^T (w_bl^T (w_q^T [text;proto])) for b=bkx-6 ----
        int b = bkx - 6;
        __shared__ float4 p4[16][64];
        __shared__ float qxs[256], qws[256];
        const float4* wq4 = (const float4*)w_q;
        const float4* wbl4 = (const float4*)w_bl;
        const float4* wk4 = (const float4*)w_k;

        float4 acc = {0.f, 0.f, 0.f, 0.f};
        #pragma unroll
        for (int j = 0; j < 35; ++j) {
            int e = w + 16 * j;
            if (e < TDIM + HID) {
                float x = (e < TDIM) ? text[b * TDIM + e] : proto[b * HID + e - TDIM];
                float4 f = wq4[(size_t)e * 64 + lane];
                acc.x += x * f.x; acc.y += x * f.y; acc.z += x * f.z; acc.w += x * f.w;
            }
        }
        p4[w][lane] = acc;
        __syncthreads();
        if (tid < 256) {
            const float* pf = (const float*)p4;
            float s = 0.f;
            #pragma unroll
            for (int ww = 0; ww < 16; ++ww) s += pf[ww * 256 + tid];
            qxs[tid] = s;
        }
        __syncthreads();
        acc.x = acc.y = acc.z = acc.w = 0.f;
        #pragma unroll
        for (int j = 0; j < 16; ++j) {
            int e = w + 16 * j;
            float x = qxs[e];
            float4 f = wbl4[(size_t)e * 64 + lane];
            acc.x += x * f.x; acc.y += x * f.y; acc.z += x * f.z; acc.w += x * f.w;
        }
        p4[w][lane] = acc;
        __syncthreads();
        if (tid < 256) {
            const float* pf = (const float*)p4;
            float s = 0.f;
            #pragma unroll
            for (int ww = 0; ww < 16; ++ww) s += pf[ww * 256 + tid];
            qws[tid] = s;
        }
        __syncthreads();
        acc.x = acc.y = acc.z = acc.w = 0.f;
        #pragma unroll
        for (int j = 0; j < 16; ++j) {
            int e = w + 16 * j;
            float x = qws[e];
            float4 f = wk4[(size_t)e * 64 + lane];
            acc.x += x * f.x; acc.y += x * f.y; acc.z += x * f.z; acc.w += x * f.w;
        }
        p4[w][lane] = acc;
        __syncthreads();
        if (tid < 256) {
            const float* pf = (const float*)p4;
            float s = 0.f;
            #pragma unroll
            for (int ww = 0; ww < 16; ++ww) s += pf[ww * 256 + tid];
            ws[OFF_U + b * HID + tid] = s;
        }
        return;
    }

    // ---- sim role ----
    __shared__ float sA[66 * LPITCH];
    __shared__ float sB[66 * LPITCH];
    __shared__ float rmin[16], rmax[16];
    int bk = bkx; int b = bk / 3; int kt = bk % 3;

    const float* dp0 = ws + OFF_DOTP + (size_t)(b * 3 + kt) * Ssz;
    for (int i = tid; i < 66 * LPITCH; i += 1024) {
        int r = i / LPITCH, col = i - r * LPITCH;
        int y = r - 3, x = col - 4;
        float s = 0.f;
        if (y >= 0 && y < Hh && x >= 0 && x < Hh) {
            int q = y * Hh + x;
            #pragma unroll
            for (int g = 0; g < 16; ++g) s += dp0[(size_t)g * 6 * Ssz + q];
        }
        sA[i] = s;
    }
    __syncthreads();
    if (kt != 1) {
        for (int idx = tid; idx < 66 * 60; idx += 1024) {
            int r = idx / 60, x = idx - 60 * r;
            int base = r * LPITCH + 4 + x;
            if (kt == 0)
                sB[base] = sA[base - 2] + sA[base - 1] + sA[base] + sA[base + 1] + sA[base + 2];
            else
                sB[base] = sA[base - 3] + sA[base - 2] + sA[base - 1] + sA[base]
                         + sA[base + 1] + sA[base + 2] + sA[base + 3];
        }
    }
    __syncthreads();
    float norm = ((kt == 0) ? (1.f / 25.f) : (1.f / 7.f)) * (1.f / (float)Ssz);
    float vals[4];
    float vmin = INFINITY, vmax = -INFINITY;
    #pragma unroll
    for (int j = 0; j < 4; ++j) {
        int q = tid + j * 1024;
        if (q < Ssz) {
            int y = q / Hh, x = q - y * Hh;
            int base = (y + 3) * LPITCH + 4 + x;
            float s;
            if (kt == 0)
                s = sB[base - 2*LPITCH] + sB[base - LPITCH] + sB[base]
                  + sB[base + LPITCH] + sB[base + 2*LPITCH];
            else if (kt == 1)
                s = sA[base - 3*LPITCH] + sA[base - 2*LPITCH] + sA[base - LPITCH]
                  + sA[base] + sA[base + LPITCH] + sA[base + 2*LPITCH] + sA[base + 3*LPITCH];
            else
                s = sB[base];
            float val = s * norm;
            vals[j] = val;
            vmin = fminf(vmin, val); vmax = fmaxf(vmax, val);
        }
    }
    #pragma unroll
    for (int m = 32; m >= 1; m >>= 1) {
        vmin = fminf(vmin, __shfl_xor(vmin, m, 64));
        vmax = fmaxf(vmax, __shfl_xor(vmax, m, 64));
    }
    if (lane == 0) { rmin[w] = vmin; rmax[w] = vmax; }
    __syncthreads();
    float mn = rmin[0], mx = rmax[0];
    #pragma unroll
    for (int ww = 1; ww < 16; ++ww) {
        mn = fminf(mn, rmin[ww]); mx = fmaxf(mx, rmax[ww]);
    }
    float inv = 1.f / (mx - mn + EPSF);
    float* np = ws + OFF_NORM + (size_t)(b * 3 + kt) * Ssz;
    #pragma unroll
    for (int j = 0; j < 4; ++j) {
        int q = tid + j * 1024;
        if (q < Ssz) np[q] = (vals[j] - mn) * inv;
    }
}

// ---------------- score strips (st 0..28) + corr-final role (st 29) ---------
__global__ void __launch_bounds__(1024)
k_score(const float* __restrict__ kin, const float* __restrict__ weight,
        float* __restrict__ ws, float* __restrict__ out) {
    int st = blockIdx.x, b = blockIdx.y;
    int tid = threadIdx.x;

    if (st == 29) {
        // ---- corr final role: one block per b ----
        __shared__ float sF[Ssz];
        float wq3 = weight[b] * (1.f / 3.f);
        const float* n0 = ws + OFF_NORM + (size_t)(b * 3 + 0) * Ssz;
        const float* n1 = ws + OFF_NORM + (size_t)(b * 3 + 1) * Ssz;
        const float* n2 = ws + OFF_NORM + (size_t)(b * 3 + 2) * Ssz;
        #pragma unroll
        for (int j = 0; j < 4; ++j) {
            int q = tid + j * 1024;
            if (q < Ssz) {
                float s = n0[q] + n1[q] + n2[q];
                sF[q] = s;
                out[b * Ssz + q] = wq3 * s;
            }
        }
        __syncthreads();
        #pragma unroll
        for (int j = 0; j < 2; ++j) {
            int o = tid + j * 1024;
            if (o >= 1189) continue;
            int O, p, outi;
            if (o < 900)       { O = 30; p = o;        outi = 7200 + b * 900 + p; }
            else if (o < 1125) { O = 15; p = o - 900;  outi = 9000 + b * 225 + p; }
            else               { O = 8;  p = o - 1125; outi = 9450 + b * 64 + p; }
            int y = p / O, x = p - y * O;
            float sc = 59.f / (float)(O - 1);
            float py = y * sc, px = x * sc;
            int y0 = (int)floorf(py), x0 = (int)floorf(px);
            int y1 = min(y0 + 1, 59), x1 = min(x0 + 1, 59);
            float wy = py - y0, wx = px - x0;
            float v = sF[y0 * 60 + x0] * (1.f - wy) * (1.f - wx)
                    + sF[y1 * 60 + x0] * wy * (1.f - wx)
                    + sF[y0 * 60 + x1] * (1.f - wy) * wx
                    + sF[y1 * 60 + x1] * wy * wx;
            out[outi] = wq3 * v;
        }
        return;
    }

    // ---- score role: 128 s-values, 8-way i-split, LDS reduce ----
    __shared__ float us[HID];
    __shared__ float part[8][128];
    if (tid < HID) us[tid] = ws[OFF_U + b * HID + tid];
    __syncthreads();
    int sl = tid & 127, pt = tid >> 7;          // pt = 0..7
    int s = st * 128 + sl;
    float a = 0.f;
    if (s < Ssz) {
        const float* kb = kin + ((size_t)b * HID + pt * 32) * Ssz + s;
        const float* up = us + pt * 32;
        #pragma unroll
        for (int i = 0; i < 32; ++i) a += up[i] * kb[(size_t)i * Ssz];
    }
    part[pt][sl] = a;
    __syncthreads();
    if (tid < 128 && st * 128 + tid < Ssz) {
        float t = 0.f;
        #pragma unroll
        for (int p = 0; p < 8; ++p) t += part[p][tid];
        ws[OFF_SCORE + (size_t)b * Ssz + st * 128 + tid] = t;
    }
}

// ---------------- kbar[b,i] = softmax(score) . k[b,i,:]  (softmax fused) ----
__global__ void k_kbar(const float* __restrict__ kin, float* __restrict__ ws) {
    int i = blockIdx.x, b = blockIdx.y;
    int tid = threadIdx.x;
    int lane = tid & 63, w = tid >> 6;
    __shared__ float r1[4], r2[4];
    const float4* s4 = (const float4*)(ws + OFF_SCORE + (size_t)b * Ssz);
    float4 sv[4]; bool act[4];
    float mx = -INFINITY;
    #pragma unroll
    for (int j = 0; j < 4; ++j) {
        int idx = tid + 256 * j;
        act[j] = idx < 900;
        if (act[j]) {
            float4 v = s4[idx];
            sv[j] = v;
            mx = fmaxf(mx, fmaxf(fmaxf(v.x, v.y), fmaxf(v.z, v.w)));
        }
    }
    #pragma unroll
    for (int m = 32; m >= 1; m >>= 1) mx = fmaxf(mx, __shfl_xor(mx, m, 64));
    if (lane == 0) r1[w] = mx;
    __syncthreads();
    mx = fmaxf(fmaxf(r1[0], r1[1]), fmaxf(r1[2], r1[3]));
    __syncthreads();
    const float4* kr = (const float4*)(kin + ((size_t)b * HID + i) * Ssz);
    float se = 0.f, wsum = 0.f;
    #pragma unroll
    for (int j = 0; j < 4; ++j) {
        if (act[j]) {
            int idx = tid + 256 * j;
            float4 v = sv[j];
            float ex = expf(v.x - mx), ey = expf(v.y - mx);
            float ez = expf(v.z - mx), ew = expf(v.w - mx);
            se += ex + ey + ez + ew;
            float4 k4 = kr[idx];
            wsum += ex * k4.x + ey * k4.y + ez * k4.z + ew * k4.w;
        }
    }
    #pragma unroll
    for (int m = 32; m >= 1; m >>= 1) {
        se += __shfl_xor(se, m, 64);
        wsum += __shfl_xor(wsum, m, 64);
    }
    if (lane == 0) { r1[w] = se; r2[w] = wsum; }
    __syncthreads();
    if (tid == 0) {
        float seT = r1[0] + r1[1] + r1[2] + r1[3];
        float wsT = r2[0] + r2[1] + r2[2] + r2[3];
        ws[OFF_KBAR + b * HID + i] = wsT / seT;
    }
}

// ---------------- out = w_proj^T (w_k kbar) + b + proto ---------------------
__global__ void __launch_bounds__(1024, 1)
k_apa_out(const float* __restrict__ w_k, const float* __restrict__ w_proj,
          const float* __restrict__ b_proj, const float* __restrict__ proto,
          const float* __restrict__ ws, float* __restrict__ out) {
    int b = blockIdx.x;
    int tid = threadIdx.x;
    int lane = tid & 63, w = tid >> 6;
    __shared__ float4 kbs[64];
    __shared__ float o1s[256];
    __shared__ float4 p4[16][64];
    const float4* wk4 = (const float4*)w_k;
    const float4* wp4 = (const float4*)w_proj;

    if (tid < 64) kbs[tid] = ((const float4*)(ws + OFF_KBAR + b * HID))[tid];
    __syncthreads();

    float4 kb4 = kbs[lane];
    #pragma unroll
    for (int r = 0; r < 16; ++r) {
        int h = w + 16 * r;
        float4 f = wk4[(size_t)h * 64 + lane];
        float p = f.x * kb4.x + f.y * kb4.y + f.z * kb4.z + f.w * kb4.w;
        #pragma unroll
        for (int m = 32; m >= 1; m >>= 1) p += __shfl_xor(p, m, 64);
        if (lane == 0) o1s[h] = p;
    }
    __syncthreads();

    float4 acc = {0.f, 0.f, 0.f, 0.f};
    #pragma unroll
    for (int j = 0; j < 16; ++j) {
        int d = w + 16 * j;
        float x = o1s[d];
        float4 f = wp4[(size_t)d * 64 + lane];
        acc.x += x * f.x; acc.y += x * f.y; acc.z += x * f.z; acc.w += x * f.w;
    }
    p4[w][lane] = acc;
    __syncthreads();
    if (tid < 256) {
        const float* pf = (const float*)p4;
        float s = 0.f;
        #pragma unroll
        for (int ww = 0; ww < 16; ++ww) s += pf[ww * 256 + tid];
        out[9578 + b * HID + tid] = s + b_proj[tid] + proto[b * HID + tid];
    }
}

extern "C" void kernel_launch(void* const* d_in, const int* in_sizes, int n_in,
                              void* d_out, int out_size, void* d_ws, size_t ws_size,
                              hipStream_t stream) {
    const float* weight = (const float*)d_in[0];
    const float* query  = (const float*)d_in[1];
    const float* supp   = (const float*)d_in[2];
    const float* masks  = (const float*)d_in[3];
    const float* kin    = (const float*)d_in[4];
    const float* text   = (const float*)d_in[5];
    const float* proto  = (const float*)d_in[6];
    const float* w_q    = (const float*)d_in[7];
    const float* w_k    = (const float*)d_in[8];
    const float* w_bl   = (const float*)d_in[9];
    const float* w_proj = (const float*)d_in[10];
    const float* b_proj = (const float*)d_in[11];
    float* out = (float*)d_out;
    float* ws  = (float*)d_ws;

    k_pool_sn2<<<dim3(4, 128, 2), 256, 0, stream>>>(supp, masks, ws);
    k_wmap<<<dim3(4, 6), 1024, 0, stream>>>(masks, ws);
    k_v<<<dim3(256, 2), 256, 0, stream>>>(supp, ws);
    k_dot<<<dim3(15, 16, 2), 256, 0, stream>>>(query, ws);
    k_sim<<<8, 1024, 0, stream>>>(text, proto, w_q, w_bl, w_k, ws);
    k_score<<<dim3(30, 2), 1024, 0, stream>>>(kin, weight, ws, out);
    k_kbar<<<dim3(HID, 2), 256, 0, stream>>>(kin, ws);
    k_apa_out<<<Bsz, 1024, 0, stream>>>(w_k, w_proj, b_proj, proto, ws, out);
}